// Round 1
// 2317.934 us; speedup vs baseline: 1.2710x; 1.2710x over previous
//
#include <hip/hip_runtime.h>
#include <stdint.h>

#define E_EDGES 400000
#define N_NODES 100000

// ---------------- workspace layout (bytes) ----------------
#define OW1P  ((size_t)0)                              // ushort[12*128*32] ie_W1 packed bf16 frag-order
#define OW2P  ((size_t)98304)                          // ushort[4*128*32]  ie_W2 packed bf16 frag-order
#define OSLR  ((size_t)524288)                         // slr packed bf16, u32[E*64]
#define ONW   (OSLR + (size_t)E_EDGES * 64 * 4)        // float[N]  node_weights
#define OMI   (ONW + (size_t)N_NODES * 4)              // float[N]  m_inv
#define OII   (OMI + (size_t)N_NODES * 4)              // float[N]  i_inv
#define ODE   (OII + (size_t)N_NODES * 4)              // float[N]  de_out
#define OFS   (ODE + (size_t)N_NODES * 4)              // float[3N] fij sums
#define OTS   (OFS + (size_t)N_NODES * 12)             // float[3N] tau sums
#define WSEND (OTS + (size_t)N_NODES * 12)

typedef __attribute__((ext_vector_type(8))) short bf16x8;
typedef __attribute__((ext_vector_type(4))) float f32x4;

// ---------------- helpers ----------------
__device__ __forceinline__ float bfu_lo(uint32_t u) { return __uint_as_float(u << 16); }
__device__ __forceinline__ float bfu_hi(uint32_t u) { return __uint_as_float(u & 0xffff0000u); }
__device__ __forceinline__ uint32_t f2bf16(float f) {
  uint32_t x = __float_as_uint(f);
  return (x + 0x7fffu + ((x >> 16) & 1u)) >> 16;   // RNE
}
__device__ __forceinline__ float wave_sum64(float v) {
#pragma unroll
  for (int off = 32; off > 0; off >>= 1) v += __shfl_xor(v, off, 64);
  return v;
}

// acc[8] pairs: a0 -> out col = lane, a1 -> out col = lane+64.
// W: fp32 row-major (Ka rows x 128 cols), read directly (L2-resident).
__device__ __forceinline__ void gemv8(const float* __restrict__ W,
                                      const float* __restrict__ xb, int xstride,
                                      int Ka, int lane, float* a0, float* a1) {
#pragma unroll 2
  for (int i = 0; i < Ka; i += 4) {
    float w0[4], w1[4];
#pragma unroll
    for (int u = 0; u < 4; ++u) {
      w0[u] = W[(size_t)(i + u) * 128 + lane];
      w1[u] = W[(size_t)(i + u) * 128 + 64 + lane];
    }
#pragma unroll
    for (int r = 0; r < 8; ++r) {
#pragma unroll
      for (int u = 0; u < 4; ++u) {
        float xv = xb[r * xstride + i + u];
        a0[r] = fmaf(xv, w0[u], a0[r]);
        a1[r] = fmaf(xv, w1[u], a1[r]);
      }
    }
  }
}

__device__ __forceinline__ void layernorm8(float* y0, float* y1, float g0, float g1,
                                           float be0, float be1) {
#pragma unroll
  for (int r = 0; r < 8; ++r) {
    float s  = wave_sum64(y0[r] + y1[r]);
    float s2 = wave_sum64(y0[r] * y0[r] + y1[r] * y1[r]);
    float mu = s * 0.0078125f;
    float var = s2 * 0.0078125f - mu * mu;
    float rstd = rsqrtf(var + 1e-5f);
    y0[r] = (y0[r] - mu) * rstd * g0 + be0;
    y1[r] = (y1[r] - mu) * rstd * g1 + be1;
  }
}

// copy 8 contiguous rows of 128 floats (4KB) global -> LDS, one wave
__device__ __forceinline__ void copy8x128(const float* __restrict__ src,
                                          float* __restrict__ dst, int lane) {
#pragma unroll
  for (int t = 0; t < 4; ++t) {
    float4 v = ((const float4*)src)[lane + 64 * t];
    ((float4*)dst)[lane + 64 * t] = v;
  }
}

// ---------------- node MLPs: nw, mi, ii, de (128->128->1), full fp32 ----------------
__global__ __launch_bounds__(256) void k_node(
    const float* __restrict__ NL,
    const float* __restrict__ nw_W1, const float* __restrict__ nw_b1,
    const float* __restrict__ nw_W2, const float* __restrict__ nw_b2,
    const float* __restrict__ mi_W1, const float* __restrict__ mi_b1,
    const float* __restrict__ mi_W2, const float* __restrict__ mi_b2,
    const float* __restrict__ ii_W1, const float* __restrict__ ii_b1,
    const float* __restrict__ ii_W2, const float* __restrict__ ii_b2,
    const float* __restrict__ de_W1, const float* __restrict__ de_b1,
    const float* __restrict__ de_W2, const float* __restrict__ de_b2,
    float* __restrict__ o_nw, float* __restrict__ o_mi, float* __restrict__ o_ii,
    float* __restrict__ o_de) {
  __shared__ float xb[4][8 * 128];
  int w = threadIdx.x >> 6, l = threadIdx.x & 63;
  int nb = blockIdx.x * 32 + w * 8;
  copy8x128(NL + (size_t)nb * 128, xb[w], l);
  __syncthreads();
  const float* W1s[4] = {nw_W1, mi_W1, ii_W1, de_W1};
  const float* B1[4] = {nw_b1, mi_b1, ii_b1, de_b1};
  const float* W2[4] = {nw_W2, mi_W2, ii_W2, de_W2};
  const float* B2[4] = {nw_b2, mi_b2, ii_b2, de_b2};
  float* OUT[4] = {o_nw, o_mi, o_ii, o_de};
#pragma unroll
  for (int m = 0; m < 4; ++m) {
    float b10 = B1[m][l], b11 = B1[m][l + 64];
    float a0[8], a1[8];
#pragma unroll
    for (int r = 0; r < 8; ++r) { a0[r] = b10; a1[r] = b11; }
    gemv8(W1s[m], xb[w], 128, 128, l, a0, a1);
    float w2a = W2[m][l], w2b = W2[m][l + 64];
    float b2 = B2[m][0];
    float y[8];
#pragma unroll
    for (int r = 0; r < 8; ++r) {
      float p = fmaxf(a0[r], 0.f) * w2a + fmaxf(a1[r], 0.f) * w2b;
      y[r] = wave_sum64(p) + b2;
    }
    if (l == 0) {
#pragma unroll
      for (int r = 0; r < 8; ++r) OUT[m][nb + r] = y[r];
    }
  }
}

// ---------------- edge encoder (ee): [||dx||,||dt||,attr] -> 128, LN ----------------
__global__ __launch_bounds__(256) void k_ee(
    const float* __restrict__ dx, const float* __restrict__ dt, const float* __restrict__ attr,
    const float* __restrict__ W1, const float* __restrict__ b1,
    const float* __restrict__ W2, const float* __restrict__ b2,
    const float* __restrict__ g, const float* __restrict__ be, float* __restrict__ elat) {
  __shared__ float xb3[4][8 * 4];
  __shared__ float hb[4][8 * 128];
  int w = threadIdx.x >> 6, l = threadIdx.x & 63;
  int base = blockIdx.x * 32 + w * 8;
  if (l < 8) {
    int e = base + l;
    float a0 = dx[e * 3], a1v = dx[e * 3 + 1], a2 = dx[e * 3 + 2];
    float t0 = dt[e * 3], t1 = dt[e * 3 + 1], t2 = dt[e * 3 + 2];
    xb3[w][l * 4 + 0] = sqrtf(a0 * a0 + a1v * a1v + a2 * a2);
    xb3[w][l * 4 + 1] = sqrtf(t0 * t0 + t1 * t1 + t2 * t2);
    xb3[w][l * 4 + 2] = attr[e];
  }
  __syncthreads();
  float b10 = b1[l], b11 = b1[l + 64];
  float a0[8], a1[8];
#pragma unroll
  for (int r = 0; r < 8; ++r) { a0[r] = b10; a1[r] = b11; }
#pragma unroll
  for (int i = 0; i < 3; ++i) {
    float w0 = W1[i * 128 + l], w1 = W1[i * 128 + 64 + l];
#pragma unroll
    for (int r = 0; r < 8; ++r) {
      float xv = xb3[w][r * 4 + i];
      a0[r] = fmaf(xv, w0, a0[r]);
      a1[r] = fmaf(xv, w1, a1[r]);
    }
  }
#pragma unroll
  for (int r = 0; r < 8; ++r) {
    hb[w][r * 128 + l] = fmaxf(a0[r], 0.f);
    hb[w][r * 128 + 64 + l] = fmaxf(a1[r], 0.f);
  }
  __syncthreads();
  float y0[8], y1[8];
  float b20 = b2[l], b21 = b2[l + 64];
#pragma unroll
  for (int r = 0; r < 8; ++r) { y0[r] = b20; y1[r] = b21; }
  gemv8(W2, hb[w], 128, 128, l, y0, y1);
  layernorm8(y0, y1, g[l], g[l + 64], be[l], be[l + 64]);
#pragma unroll
  for (int r = 0; r < 8; ++r) {
    size_t o = (size_t)(base + r) * 128;
    elat[o + l] = y0[r];
    elat[o + 64 + l] = y1[r];
  }
}

// ---------------- edge-feature encoder (ef): 9 -> 128, LN; writes slr = s_lat + r_lat (bf16 pairs)
__global__ __launch_bounds__(256) void k_ef(
    const float* __restrict__ va, const float* __restrict__ vb, const float* __restrict__ vc,
    const float* __restrict__ svt, const float* __restrict__ svtm1, const float* __restrict__ swt,
    const float* __restrict__ rvt, const float* __restrict__ rvtm1, const float* __restrict__ rwt,
    const float* __restrict__ W1, const float* __restrict__ b1,
    const float* __restrict__ W2, const float* __restrict__ b2,
    const float* __restrict__ g, const float* __restrict__ be, uint32_t* __restrict__ slrp) {
  __shared__ float xb9[4][8 * 12];
  __shared__ float hb[4][8 * 128];
  int w = threadIdx.x >> 6, l = threadIdx.x & 63;
  int base = blockIdx.x * 16 + w * 4;  // 4 edges, rows 0..3 = sf, rows 4..7 = rf
  if (l < 8) {
    int e = base + (l & 3);
    bool isR = l >= 4;
    const float* p0 = isR ? rvt : svt;
    const float* p1 = isR ? rvtm1 : svtm1;
    const float* p2 = isR ? rwt : swt;
    float sgn = isR ? -1.f : 1.f;
    float ax = va[e * 3], ay = va[e * 3 + 1], az = va[e * 3 + 2];
    float bx = vb[e * 3], by = vb[e * 3 + 1], bz = vb[e * 3 + 2];
    float cx = vc[e * 3], cy = vc[e * 3 + 1], cz = vc[e * 3 + 2];
    const float* ps[3] = {p0, p1, p2};
#pragma unroll
    for (int q = 0; q < 3; ++q) {
      float vx = ps[q][e * 3], vy = ps[q][e * 3 + 1], vz = ps[q][e * 3 + 2];
      xb9[w][l * 12 + q * 3 + 0] = sgn * (vx * ax + vy * ay + vz * az);
      xb9[w][l * 12 + q * 3 + 1] = sgn * (vx * bx + vy * by + vz * bz);
      xb9[w][l * 12 + q * 3 + 2] = sgn * (vx * cx + vy * cy + vz * cz);
    }
  }
  __syncthreads();
  float b10 = b1[l], b11 = b1[l + 64];
  float a0[8], a1[8];
#pragma unroll
  for (int r = 0; r < 8; ++r) { a0[r] = b10; a1[r] = b11; }
#pragma unroll
  for (int i = 0; i < 9; ++i) {
    float w0 = W1[i * 128 + l], w1 = W1[i * 128 + 64 + l];
#pragma unroll
    for (int r = 0; r < 8; ++r) {
      float xv = xb9[w][r * 12 + i];
      a0[r] = fmaf(xv, w0, a0[r]);
      a1[r] = fmaf(xv, w1, a1[r]);
    }
  }
#pragma unroll
  for (int r = 0; r < 8; ++r) {
    hb[w][r * 128 + l] = fmaxf(a0[r], 0.f);
    hb[w][r * 128 + 64 + l] = fmaxf(a1[r], 0.f);
  }
  __syncthreads();
  float y0[8], y1[8];
  float b20 = b2[l], b21 = b2[l + 64];
#pragma unroll
  for (int r = 0; r < 8; ++r) { y0[r] = b20; y1[r] = b21; }
  gemv8(W2, hb[w], 128, 128, l, y0, y1);
  layernorm8(y0, y1, g[l], g[l + 64], be[l], be[l + 64]);
#pragma unroll
  for (int r = 0; r < 4; ++r) {
    float s0 = y0[r] + y0[r + 4];
    float s1 = y1[r] + y1[r + 4];
    slrp[(size_t)(base + r) * 64 + l] = f2bf16(s0) | (f2bf16(s1) << 16);
  }
}

// ---------------- prep: pack ie_W1/ie_W2 into bf16 MFMA frag order ----------------
// W1P layout: ushort[ks][c][kin], ks in [0,12), c in [0,128), kin in [0,32).
//   X col order kx: [0,128) is slr-interleaved (kx=2l -> orig k=l, kx=2l+1 -> orig k=64+l),
//   [128,384) is identity. W1P holds W1[korig(ks*32+kin)][c].
// W2P layout: ushort[ks][c][kin], ks in [0,4); H is in natural col order -> identity.
__global__ __launch_bounds__(256) void k_prep(const float* __restrict__ W1,
                                              const float* __restrict__ W2,
                                              unsigned short* __restrict__ W1P,
                                              unsigned short* __restrict__ W2P) {
  int i = blockIdx.x * 256 + threadIdx.x;   // grid covers 49152
  if (i < 12 * 128 * 32) {
    int kin = i & 31, c = (i >> 5) & 127, ks = i >> 12;
    int kx = ks * 32 + kin;
    int ko = (kx < 128) ? ((kx & 1) * 64 + (kx >> 1)) : kx;
    W1P[i] = (unsigned short)f2bf16(W1[(size_t)ko * 128 + c]);
  }
  if (i < 4 * 128 * 32) {
    int kin = i & 31, c = (i >> 5) & 127, ks = i >> 12;
    W2P[i] = (unsigned short)f2bf16(W2[(size_t)(ks * 32 + kin) * 128 + c]);
  }
}

// ---------------- interaction encoder (ie): MFMA bf16, 384 -> 128 -> 128, LN ----------------
// 64 edges/block, 4 waves; wave w owns output cols [w*32, w*32+32).
// LDS: X bf16 [64][384] swizzled (49152 B) ; H bf16 [64][128] swizzled (16384 B) = 65536 B.
// Y fp32 [64][132] reuses the X region after the H barrier.
// Swizzle: byte ^= (row&7)<<4 — row pitches (768B / 256B) are 0 mod 128 banks, which would be
// a 16-way conflict on the ds_read_b128 A-frag loads (G4 / T2); XOR spreads 8 rows over 8 slots.
__global__ __launch_bounds__(256) void k_ie_mfma(
    const int* __restrict__ ei, const float* __restrict__ NL,
    const uint32_t* __restrict__ slrp,
    const unsigned short* __restrict__ W1P, const unsigned short* __restrict__ W2P,
    const float* __restrict__ b1, const float* __restrict__ b2,
    const float* __restrict__ g, const float* __restrict__ be,
    float* __restrict__ il) {
  __shared__ uint8_t lds[65536];
  int tid = threadIdx.x;
  int w = tid >> 6, l = tid & 63;
  int lrow = l & 15, lk = l >> 4;
  int base = blockIdx.x * 64;

  // edge indices once per block (H region doubles as scratch during staging)
  int* eis = (int*)(lds + 49152);
  int* eit = eis + 64;
  if (tid < 64) {
    eis[tid] = ei[base + tid];
    eit[tid] = ei[E_EDGES + base + tid];
  }
  __syncthreads();

  // ---- stage X (bf16, swizzled) ----
  // seg A: slr packed u32 -> X cols [0,128) (interleaved order, matched by W1P perm)
#pragma unroll
  for (int i = tid; i < 64 * 64; i += 256) {
    int r = i >> 6, c = i & 63;
    uint32_t bo = ((uint32_t)r * 768 + (uint32_t)c * 4) ^ ((uint32_t)(r & 7) << 4);
    *(uint32_t*)(lds + bo) = slrp[(size_t)(base + r) * 64 + c];
  }
  // seg B: NL[s]+NL[t] -> X cols [128,256)
  const float2* NL2 = (const float2*)NL;
#pragma unroll
  for (int i = tid; i < 64 * 64; i += 256) {
    int r = i >> 6, c = i & 63;
    float2 a = NL2[(size_t)eis[r] * 64 + c];
    float2 bq = NL2[(size_t)eit[r] * 64 + c];
    uint32_t p = f2bf16(a.x + bq.x) | (f2bf16(a.y + bq.y) << 16);
    uint32_t bo = ((uint32_t)r * 768 + 256u + (uint32_t)c * 4) ^ ((uint32_t)(r & 7) << 4);
    *(uint32_t*)(lds + bo) = p;
  }
  // seg C: e_lat -> X cols [256,384)
  const float2* IL2 = (const float2*)il;
#pragma unroll
  for (int i = tid; i < 64 * 64; i += 256) {
    int r = i >> 6, c = i & 63;
    float2 a = IL2[(size_t)(base + r) * 64 + c];
    uint32_t p = f2bf16(a.x) | (f2bf16(a.y) << 16);
    uint32_t bo = ((uint32_t)r * 768 + 512u + (uint32_t)c * 4) ^ ((uint32_t)(r & 7) << 4);
    *(uint32_t*)(lds + bo) = p;
  }

  // register-resident W2 frags + per-col biases (independent of staging)
  int wc = w * 32;
  bf16x8 w2f[4][2];
#pragma unroll
  for (int ks = 0; ks < 4; ++ks)
#pragma unroll
    for (int ct = 0; ct < 2; ++ct)
      w2f[ks][ct] = *(const bf16x8*)(W2P + ((size_t)(ks * 128 + wc + ct * 16 + lrow) * 32 + lk * 8));
  float b1c0 = b1[wc + lrow], b1c1 = b1[wc + 16 + lrow];
  float b2c0 = b2[wc + lrow], b2c1 = b2[wc + 16 + lrow];

  __syncthreads();

  // ---- GEMM1: 64 rows x 32 cols (per wave), K=384 ----
  f32x4 acc[4][2];
#pragma unroll
  for (int rt = 0; rt < 4; ++rt)
#pragma unroll
    for (int ct = 0; ct < 2; ++ct) acc[rt][ct] = (f32x4){0.f, 0.f, 0.f, 0.f};
#pragma unroll 2
  for (int ks = 0; ks < 12; ++ks) {
    bf16x8 bf0 = *(const bf16x8*)(W1P + ((size_t)(ks * 128 + wc + lrow) * 32 + lk * 8));
    bf16x8 bf1 = *(const bf16x8*)(W1P + ((size_t)(ks * 128 + wc + 16 + lrow) * 32 + lk * 8));
#pragma unroll
    for (int rt = 0; rt < 4; ++rt) {
      int row = rt * 16 + lrow;
      uint32_t bo = ((uint32_t)row * 768 + (uint32_t)(ks * 64 + lk * 16)) ^ ((uint32_t)(row & 7) << 4);
      bf16x8 af = *(const bf16x8*)(lds + bo);
      acc[rt][0] = __builtin_amdgcn_mfma_f32_16x16x32_bf16(af, bf0, acc[rt][0], 0, 0, 0);
      acc[rt][1] = __builtin_amdgcn_mfma_f32_16x16x32_bf16(af, bf1, acc[rt][1], 0, 0, 0);
    }
  }

  // ---- H = relu(acc + b1) -> bf16 LDS (swizzled) ----
  // D layout: col = lane&15, row = (lane>>4)*4 + q  [m89/m91 verified]
#pragma unroll
  for (int rt = 0; rt < 4; ++rt)
#pragma unroll
    for (int ct = 0; ct < 2; ++ct) {
      float bc = ct ? b1c1 : b1c0;
      int col = wc + ct * 16 + lrow;
#pragma unroll
      for (int q = 0; q < 4; ++q) {
        int row = rt * 16 + lk * 4 + q;
        float h = fmaxf(acc[rt][ct][q] + bc, 0.f);
        uint32_t bo = ((uint32_t)row * 256 + (uint32_t)col * 2) ^ ((uint32_t)(row & 7) << 4);
        *(unsigned short*)(lds + 49152 + bo) = (unsigned short)f2bf16(h);
      }
    }
  __syncthreads();

  // ---- GEMM2: K=128 ----
  f32x4 acc2[4][2];
#pragma unroll
  for (int rt = 0; rt < 4; ++rt)
#pragma unroll
    for (int ct = 0; ct < 2; ++ct) acc2[rt][ct] = (f32x4){0.f, 0.f, 0.f, 0.f};
#pragma unroll
  for (int ks = 0; ks < 4; ++ks) {
#pragma unroll
    for (int rt = 0; rt < 4; ++rt) {
      int row = rt * 16 + lrow;
      uint32_t bo = ((uint32_t)row * 256 + (uint32_t)(ks * 64 + lk * 16)) ^ ((uint32_t)(row & 7) << 4);
      bf16x8 af = *(const bf16x8*)(lds + 49152 + bo);
      acc2[rt][0] = __builtin_amdgcn_mfma_f32_16x16x32_bf16(af, w2f[ks][0], acc2[rt][0], 0, 0, 0);
      acc2[rt][1] = __builtin_amdgcn_mfma_f32_16x16x32_bf16(af, w2f[ks][1], acc2[rt][1], 0, 0, 0);
    }
  }

  // ---- Y = acc2 + b2 -> fp32 LDS (reuses X region; all X reads completed at the H barrier) ----
  float* Ys = (float*)lds;   // pitch 132 floats (132 % 32 == 4 -> write groups spread, G4)
#pragma unroll
  for (int rt = 0; rt < 4; ++rt)
#pragma unroll
    for (int ct = 0; ct < 2; ++ct) {
      float bc = ct ? b2c1 : b2c0;
      int col = wc + ct * 16 + lrow;
#pragma unroll
      for (int q = 0; q < 4; ++q) {
        int row = rt * 16 + lk * 4 + q;
        Ys[row * 132 + col] = acc2[rt][ct][q] + bc;
      }
    }
  __syncthreads();

  // ---- LayerNorm (wave-parallel, 16 rows/wave) + store ----
  float gl0 = g[l], gl1 = g[l + 64], bl0 = be[l], bl1 = be[l + 64];
#pragma unroll
  for (int r16 = 0; r16 < 16; ++r16) {
    int row = w * 16 + r16;
    float y0 = Ys[row * 132 + l], y1 = Ys[row * 132 + 64 + l];
    float s = wave_sum64(y0 + y1);
    float s2 = wave_sum64(y0 * y0 + y1 * y1);
    float mu = s * 0.0078125f;
    float var = s2 * 0.0078125f - mu * mu;
    float rstd = rsqrtf(var + 1e-5f);
    size_t o = (size_t)(base + row) * 128;
    il[o + l] = (y0 - mu) * rstd * gl0 + bl0;
    il[o + 64 + l] = (y1 - mu) * rstd * gl1 + bl1;
  }
}

// ---------------- decoder heads + physics + scatter ----------------
template <int NK>
__device__ __forceinline__ void dec_mlp(const float* __restrict__ W1,
                                        const float* __restrict__ b1,
                                        const float* __restrict__ W2,
                                        const float* __restrict__ b2,
                                        const float* __restrict__ xbw, float* __restrict__ dbw,
                                        int l, int slot0) {
  float b10 = b1[l], b11 = b1[l + 64];
  float a0[8], a1[8];
#pragma unroll
  for (int r = 0; r < 8; ++r) { a0[r] = b10; a1[r] = b11; }
  gemv8(W1, xbw, 128, 128, l, a0, a1);
  float w2lo[NK], w2hi[NK];
#pragma unroll
  for (int k = 0; k < NK; ++k) {
    w2lo[k] = W2[l * NK + k];
    w2hi[k] = W2[(l + 64) * NK + k];
  }
#pragma unroll
  for (int r = 0; r < 8; ++r) {
    float h0 = fmaxf(a0[r], 0.f), h1 = fmaxf(a1[r], 0.f);
#pragma unroll
    for (int k = 0; k < NK; ++k) {
      float p = wave_sum64(h0 * w2lo[k] + h1 * w2hi[k]);
      if (l == 0) dbw[r * 8 + slot0 + k] = p + b2[k];
    }
  }
}

__global__ __launch_bounds__(256) void k_dec(
    const int* __restrict__ ei, const float* __restrict__ il,
    const float* __restrict__ i1W1, const float* __restrict__ i1b1,
    const float* __restrict__ i1W2, const float* __restrict__ i1b2,
    const float* __restrict__ i2W1, const float* __restrict__ i2b1,
    const float* __restrict__ i2W2, const float* __restrict__ i2b2,
    const float* __restrict__ fsW1, const float* __restrict__ fsb1,
    const float* __restrict__ fsW2, const float* __restrict__ fsb2,
    const float* __restrict__ nw, const float* __restrict__ spos, const float* __restrict__ rpos,
    const float* __restrict__ va, const float* __restrict__ vb, const float* __restrict__ vc,
    float* __restrict__ fsum, float* __restrict__ tsum) {
  __shared__ float xb[4][8 * 128];
  __shared__ float db[4][8 * 8];  // per row: 0-2 coeff_f, 3-5 coeff_a, 6 lambda
  int w = threadIdx.x >> 6, l = threadIdx.x & 63;
  int base = blockIdx.x * 32 + w * 8;
  copy8x128(il + (size_t)base * 128, xb[w], l);
  __syncthreads();
  dec_mlp<3>(i1W1, i1b1, i1W2, i1b2, xb[w], db[w], l, 0);
  dec_mlp<3>(i2W1, i2b1, i2W2, i2b2, xb[w], db[w], l, 3);
  dec_mlp<1>(fsW1, fsb1, fsW2, fsb2, xb[w], db[w], l, 6);
  __syncthreads();
  if (l < 8) {
    int e = base + l;
    int s = ei[e], t = ei[E_EDGES + e];
    float cf0 = db[w][l * 8 + 0], cf1 = db[w][l * 8 + 1], cf2 = db[w][l * 8 + 2];
    float ca0 = db[w][l * 8 + 3], ca1 = db[w][l * 8 + 4], ca2 = db[w][l * 8 + 5];
    float lam = db[w][l * 8 + 6];
    float ax = va[e * 3], ay = va[e * 3 + 1], az = va[e * 3 + 2];
    float bx = vb[e * 3], by = vb[e * 3 + 1], bz = vb[e * 3 + 2];
    float cx = vc[e * 3], cy = vc[e * 3 + 1], cz = vc[e * 3 + 2];
    float fx = cf0 * ax + cf1 * bx + cf2 * cx;
    float fy = cf0 * ay + cf1 * by + cf2 * cy;
    float fz = cf0 * az + cf1 * bz + cf2 * cz;
    float gx = ca0 * ax + ca1 * bx + ca2 * cx;
    float gy = ca0 * ay + ca1 * by + ca2 * cy;
    float gz = ca0 * az + ca1 * bz + ca2 * cz;
    float wsn = nw[s], wrn = nw[t];
    float sx = spos[e * 3], sy = spos[e * 3 + 1], sz = spos[e * 3 + 2];
    float rx = rpos[e * 3], ry = rpos[e * 3 + 1], rz = rpos[e * 3 + 2];
    float inv = 1.f / (wsn + wrn);
    float r0x = (wsn * sx + wrn * rx) * inv;
    float r0y = (wsn * sy + wrn * ry) * inv;
    float r0z = (wsn * sz + wrn * rz) * inv;
    float ddx = rx - r0x, ddy = ry - r0y, ddz = rz - r0z;
    float cxx = ddy * fz - ddz * fy;
    float cyy = ddz * fx - ddx * fz;
    float czz = ddx * fy - ddy * fx;
    float tx = gx - cxx * lam, ty = gy - cyy * lam, tz = gz - czz * lam;
    atomicAdd(&fsum[(size_t)t * 3 + 0], fx);
    atomicAdd(&fsum[(size_t)t * 3 + 1], fy);
    atomicAdd(&fsum[(size_t)t * 3 + 2], fz);
    atomicAdd(&tsum[(size_t)t * 3 + 0], tx);
    atomicAdd(&tsum[(size_t)t * 3 + 1], ty);
    atomicAdd(&tsum[(size_t)t * 3 + 2], tz);
  }
}

// ---------------- final node combine ----------------
__global__ __launch_bounds__(256) void k_final(const float* __restrict__ mi,
                                               const float* __restrict__ ii,
                                               const float* __restrict__ de,
                                               const float* __restrict__ fsum,
                                               const float* __restrict__ tsum,
                                               float* __restrict__ out) {
  int n = blockIdx.x * 256 + threadIdx.x;
  if (n >= N_NODES) return;
  float m = mi[n], iv = ii[n], d = de[n];
#pragma unroll
  for (int c = 0; c < 3; ++c) {
    out[(size_t)n * 3 + c] = m * fsum[(size_t)n * 3 + c] + d;
    out[(size_t)3 * N_NODES + (size_t)n * 3 + c] = iv * tsum[(size_t)n * 3 + c];
  }
}

// ---------------- launch ----------------
extern "C" void kernel_launch(void* const* d_in, const int* in_sizes, int n_in, void* d_out,
                              int out_size, void* d_ws, size_t ws_size, hipStream_t stream) {
  if (ws_size < WSEND) return;  // insufficient scratch; bail (will show as wrong output)

  const int* ei = (const int*)d_in[0];
  const float* spos = (const float*)d_in[1];
  const float* rpos = (const float*)d_in[2];
  const float* dx = (const float*)d_in[3];
  const float* dt = (const float*)d_in[4];
  const float* va = (const float*)d_in[5];
  const float* vb = (const float*)d_in[6];
  const float* vc = (const float*)d_in[7];
  const float* svt = (const float*)d_in[8];
  const float* svtm1 = (const float*)d_in[9];
  const float* swt = (const float*)d_in[10];
  const float* rvt = (const float*)d_in[11];
  const float* rvtm1 = (const float*)d_in[12];
  const float* rwt = (const float*)d_in[13];
  const float* attr = (const float*)d_in[14];
  const float* NL = (const float*)d_in[15];
  const float* ef_W1 = (const float*)d_in[16];
  const float* ef_b1 = (const float*)d_in[17];
  const float* ef_W2 = (const float*)d_in[18];
  const float* ef_b2 = (const float*)d_in[19];
  const float* ef_g = (const float*)d_in[20];
  const float* ef_b = (const float*)d_in[21];
  const float* ee_W1 = (const float*)d_in[22];
  const float* ee_b1 = (const float*)d_in[23];
  const float* ee_W2 = (const float*)d_in[24];
  const float* ee_b2 = (const float*)d_in[25];
  const float* ee_g = (const float*)d_in[26];
  const float* ee_b = (const float*)d_in[27];
  const float* ie_W1 = (const float*)d_in[28];
  const float* ie_b1 = (const float*)d_in[29];
  const float* ie_W2 = (const float*)d_in[30];
  const float* ie_b2 = (const float*)d_in[31];
  const float* ie_g = (const float*)d_in[32];
  const float* ie_b = (const float*)d_in[33];
  const float* i1_W1 = (const float*)d_in[34];
  const float* i1_b1 = (const float*)d_in[35];
  const float* i1_W2 = (const float*)d_in[36];
  const float* i1_b2 = (const float*)d_in[37];
  const float* i2_W1 = (const float*)d_in[38];
  const float* i2_b1 = (const float*)d_in[39];
  const float* i2_W2 = (const float*)d_in[40];
  const float* i2_b2 = (const float*)d_in[41];
  const float* fs_W1 = (const float*)d_in[42];
  const float* fs_b1 = (const float*)d_in[43];
  const float* fs_W2 = (const float*)d_in[44];
  const float* fs_b2 = (const float*)d_in[45];
  const float* nw_W1 = (const float*)d_in[46];
  const float* nw_b1 = (const float*)d_in[47];
  const float* nw_W2 = (const float*)d_in[48];
  const float* nw_b2 = (const float*)d_in[49];
  const float* mi_W1 = (const float*)d_in[50];
  const float* mi_b1 = (const float*)d_in[51];
  const float* mi_W2 = (const float*)d_in[52];
  const float* mi_b2 = (const float*)d_in[53];
  const float* ii_W1 = (const float*)d_in[54];
  const float* ii_b1 = (const float*)d_in[55];
  const float* ii_W2 = (const float*)d_in[56];
  const float* ii_b2 = (const float*)d_in[57];
  const float* de_W1 = (const float*)d_in[58];
  const float* de_b1 = (const float*)d_in[59];
  const float* de_W2 = (const float*)d_in[60];
  const float* de_b2 = (const float*)d_in[61];

  float* out = (float*)d_out;
  char* ws = (char*)d_ws;
  unsigned short* W1P = (unsigned short*)(ws + OW1P);
  unsigned short* W2P = (unsigned short*)(ws + OW2P);
  uint32_t* slrp = (uint32_t*)(ws + OSLR);
  float* o_nw = (float*)(ws + ONW);
  float* o_mi = (float*)(ws + OMI);
  float* o_ii = (float*)(ws + OII);
  float* o_de = (float*)(ws + ODE);
  float* fsum = (float*)(ws + OFS);
  float* tsum = (float*)(ws + OTS);
  float* il = out + 6 * N_NODES;  // interaction_latent region (also e_lat temp)

  hipMemsetAsync(ws + OFS, 0, (size_t)N_NODES * 24, stream);  // fsum + tsum

  hipLaunchKernelGGL(k_prep, dim3(192), dim3(256), 0, stream, ie_W1, ie_W2, W1P, W2P);

  hipLaunchKernelGGL(k_node, dim3(N_NODES / 32), dim3(256), 0, stream, NL,
                     nw_W1, nw_b1, nw_W2, nw_b2, mi_W1, mi_b1, mi_W2, mi_b2,
                     ii_W1, ii_b1, ii_W2, ii_b2, de_W1, de_b1, de_W2, de_b2,
                     o_nw, o_mi, o_ii, o_de);

  hipLaunchKernelGGL(k_ee, dim3(E_EDGES / 32), dim3(256), 0, stream, dx, dt, attr, ee_W1, ee_b1,
                     ee_W2, ee_b2, ee_g, ee_b, il);

  hipLaunchKernelGGL(k_ef, dim3(E_EDGES / 16), dim3(256), 0, stream, va, vb, vc, svt, svtm1, swt,
                     rvt, rvtm1, rwt, ef_W1, ef_b1, ef_W2, ef_b2, ef_g, ef_b, slrp);

  hipLaunchKernelGGL(k_ie_mfma, dim3(E_EDGES / 64), dim3(256), 0, stream, ei, NL, slrp,
                     W1P, W2P, ie_b1, ie_b2, ie_g, ie_b, il);

  hipLaunchKernelGGL(k_dec, dim3(E_EDGES / 32), dim3(256), 0, stream, ei, il, i1_W1, i1_b1,
                     i1_W2, i1_b2, i2_W1, i2_b1, i2_W2, i2_b2, fs_W1, fs_b1, fs_W2,
                     fs_b2, o_nw, spos, rpos, va, vb, vc, fsum, tsum);

  hipLaunchKernelGGL(k_final, dim3((N_NODES + 255) / 256), dim3(256), 0, stream, o_mi, o_ii, o_de,
                     fsum, tsum, out);
}

// Round 2
// 1842.459 us; speedup vs baseline: 1.5990x; 1.2581x over previous
//
#include <hip/hip_runtime.h>
#include <stdint.h>

#define E_EDGES 400000
#define N_NODES 100000

// ---------------- workspace layout (bytes) ----------------
#define OW1P  ((size_t)0)                              // ushort[12*128*32] ie_W1 packed bf16 frag-order
#define OW2P  ((size_t)98304)                          // ushort[4*128*32]  ie_W2 packed bf16 frag-order
#define OW1D  ((size_t)131072)                         // ushort[4*384*32]  dec W1cat packed bf16
#define OW2D  ((size_t)229376)                         // ushort[12*16*32]  dec W2cat packed bf16
#define OSLR  ((size_t)524288)                         // slr packed bf16, u32[E*64]
#define ONW   (OSLR + (size_t)E_EDGES * 64 * 4)        // float[N]  node_weights
#define OMI   (ONW + (size_t)N_NODES * 4)              // float[N]  m_inv
#define OII   (OMI + (size_t)N_NODES * 4)              // float[N]  i_inv
#define ODE   (OII + (size_t)N_NODES * 4)              // float[N]  de_out
#define OFS   (ODE + (size_t)N_NODES * 4)              // float[3N] fij sums
#define OTS   (OFS + (size_t)N_NODES * 12)             // float[3N] tau sums
#define WSEND (OTS + (size_t)N_NODES * 12)

typedef __attribute__((ext_vector_type(8))) short bf16x8;
typedef __attribute__((ext_vector_type(4))) float f32x4;

// ---------------- helpers ----------------
__device__ __forceinline__ float bfu_lo(uint32_t u) { return __uint_as_float(u << 16); }
__device__ __forceinline__ float bfu_hi(uint32_t u) { return __uint_as_float(u & 0xffff0000u); }
__device__ __forceinline__ uint32_t f2bf16(float f) {
  uint32_t x = __float_as_uint(f);
  return (x + 0x7fffu + ((x >> 16) & 1u)) >> 16;   // RNE
}
__device__ __forceinline__ float wave_sum64(float v) {
#pragma unroll
  for (int off = 32; off > 0; off >>= 1) v += __shfl_xor(v, off, 64);
  return v;
}

// acc[8] pairs: a0 -> out col = lane, a1 -> out col = lane+64.
// W: fp32 row-major (Ka rows x 128 cols), read directly (L2-resident).
__device__ __forceinline__ void gemv8(const float* __restrict__ W,
                                      const float* __restrict__ xb, int xstride,
                                      int Ka, int lane, float* a0, float* a1) {
#pragma unroll 2
  for (int i = 0; i < Ka; i += 4) {
    float w0[4], w1[4];
#pragma unroll
    for (int u = 0; u < 4; ++u) {
      w0[u] = W[(size_t)(i + u) * 128 + lane];
      w1[u] = W[(size_t)(i + u) * 128 + 64 + lane];
    }
#pragma unroll
    for (int r = 0; r < 8; ++r) {
#pragma unroll
      for (int u = 0; u < 4; ++u) {
        float xv = xb[r * xstride + i + u];
        a0[r] = fmaf(xv, w0[u], a0[r]);
        a1[r] = fmaf(xv, w1[u], a1[r]);
      }
    }
  }
}

__device__ __forceinline__ void layernorm8(float* y0, float* y1, float g0, float g1,
                                           float be0, float be1) {
#pragma unroll
  for (int r = 0; r < 8; ++r) {
    float s  = wave_sum64(y0[r] + y1[r]);
    float s2 = wave_sum64(y0[r] * y0[r] + y1[r] * y1[r]);
    float mu = s * 0.0078125f;
    float var = s2 * 0.0078125f - mu * mu;
    float rstd = rsqrtf(var + 1e-5f);
    y0[r] = (y0[r] - mu) * rstd * g0 + be0;
    y1[r] = (y1[r] - mu) * rstd * g1 + be1;
  }
}

// copy 8 contiguous rows of 128 floats (4KB) global -> LDS, one wave
__device__ __forceinline__ void copy8x128(const float* __restrict__ src,
                                          float* __restrict__ dst, int lane) {
#pragma unroll
  for (int t = 0; t < 4; ++t) {
    float4 v = ((const float4*)src)[lane + 64 * t];
    ((float4*)dst)[lane + 64 * t] = v;
  }
}

// ---------------- node MLPs: nw, mi, ii, de (128->128->1), full fp32 ----------------
__global__ __launch_bounds__(256) void k_node(
    const float* __restrict__ NL,
    const float* __restrict__ nw_W1, const float* __restrict__ nw_b1,
    const float* __restrict__ nw_W2, const float* __restrict__ nw_b2,
    const float* __restrict__ mi_W1, const float* __restrict__ mi_b1,
    const float* __restrict__ mi_W2, const float* __restrict__ mi_b2,
    const float* __restrict__ ii_W1, const float* __restrict__ ii_b1,
    const float* __restrict__ ii_W2, const float* __restrict__ ii_b2,
    const float* __restrict__ de_W1, const float* __restrict__ de_b1,
    const float* __restrict__ de_W2, const float* __restrict__ de_b2,
    float* __restrict__ o_nw, float* __restrict__ o_mi, float* __restrict__ o_ii,
    float* __restrict__ o_de) {
  __shared__ float xb[4][8 * 128];
  int w = threadIdx.x >> 6, l = threadIdx.x & 63;
  int nb = blockIdx.x * 32 + w * 8;
  copy8x128(NL + (size_t)nb * 128, xb[w], l);
  __syncthreads();
  const float* W1s[4] = {nw_W1, mi_W1, ii_W1, de_W1};
  const float* B1[4] = {nw_b1, mi_b1, ii_b1, de_b1};
  const float* W2[4] = {nw_W2, mi_W2, ii_W2, de_W2};
  const float* B2[4] = {nw_b2, mi_b2, ii_b2, de_b2};
  float* OUT[4] = {o_nw, o_mi, o_ii, o_de};
#pragma unroll
  for (int m = 0; m < 4; ++m) {
    float b10 = B1[m][l], b11 = B1[m][l + 64];
    float a0[8], a1[8];
#pragma unroll
    for (int r = 0; r < 8; ++r) { a0[r] = b10; a1[r] = b11; }
    gemv8(W1s[m], xb[w], 128, 128, l, a0, a1);
    float w2a = W2[m][l], w2b = W2[m][l + 64];
    float b2 = B2[m][0];
    float y[8];
#pragma unroll
    for (int r = 0; r < 8; ++r) {
      float p = fmaxf(a0[r], 0.f) * w2a + fmaxf(a1[r], 0.f) * w2b;
      y[r] = wave_sum64(p) + b2;
    }
    if (l == 0) {
#pragma unroll
      for (int r = 0; r < 8; ++r) OUT[m][nb + r] = y[r];
    }
  }
}

// ---------------- edge encoder (ee): [||dx||,||dt||,attr] -> 128, LN ----------------
__global__ __launch_bounds__(256) void k_ee(
    const float* __restrict__ dx, const float* __restrict__ dt, const float* __restrict__ attr,
    const float* __restrict__ W1, const float* __restrict__ b1,
    const float* __restrict__ W2, const float* __restrict__ b2,
    const float* __restrict__ g, const float* __restrict__ be, float* __restrict__ elat) {
  __shared__ float xb3[4][8 * 4];
  __shared__ float hb[4][8 * 128];
  int w = threadIdx.x >> 6, l = threadIdx.x & 63;
  int base = blockIdx.x * 32 + w * 8;
  if (l < 8) {
    int e = base + l;
    float a0 = dx[e * 3], a1v = dx[e * 3 + 1], a2 = dx[e * 3 + 2];
    float t0 = dt[e * 3], t1 = dt[e * 3 + 1], t2 = dt[e * 3 + 2];
    xb3[w][l * 4 + 0] = sqrtf(a0 * a0 + a1v * a1v + a2 * a2);
    xb3[w][l * 4 + 1] = sqrtf(t0 * t0 + t1 * t1 + t2 * t2);
    xb3[w][l * 4 + 2] = attr[e];
  }
  __syncthreads();
  float b10 = b1[l], b11 = b1[l + 64];
  float a0[8], a1[8];
#pragma unroll
  for (int r = 0; r < 8; ++r) { a0[r] = b10; a1[r] = b11; }
#pragma unroll
  for (int i = 0; i < 3; ++i) {
    float w0 = W1[i * 128 + l], w1 = W1[i * 128 + 64 + l];
#pragma unroll
    for (int r = 0; r < 8; ++r) {
      float xv = xb3[w][r * 4 + i];
      a0[r] = fmaf(xv, w0, a0[r]);
      a1[r] = fmaf(xv, w1, a1[r]);
    }
  }
#pragma unroll
  for (int r = 0; r < 8; ++r) {
    hb[w][r * 128 + l] = fmaxf(a0[r], 0.f);
    hb[w][r * 128 + 64 + l] = fmaxf(a1[r], 0.f);
  }
  __syncthreads();
  float y0[8], y1[8];
  float b20 = b2[l], b21 = b2[l + 64];
#pragma unroll
  for (int r = 0; r < 8; ++r) { y0[r] = b20; y1[r] = b21; }
  gemv8(W2, hb[w], 128, 128, l, y0, y1);
  layernorm8(y0, y1, g[l], g[l + 64], be[l], be[l + 64]);
#pragma unroll
  for (int r = 0; r < 8; ++r) {
    size_t o = (size_t)(base + r) * 128;
    elat[o + l] = y0[r];
    elat[o + 64 + l] = y1[r];
  }
}

// ---------------- edge-feature encoder (ef): 9 -> 128, LN; writes slr = s_lat + r_lat (bf16 pairs)
__global__ __launch_bounds__(256) void k_ef(
    const float* __restrict__ va, const float* __restrict__ vb, const float* __restrict__ vc,
    const float* __restrict__ svt, const float* __restrict__ svtm1, const float* __restrict__ swt,
    const float* __restrict__ rvt, const float* __restrict__ rvtm1, const float* __restrict__ rwt,
    const float* __restrict__ W1, const float* __restrict__ b1,
    const float* __restrict__ W2, const float* __restrict__ b2,
    const float* __restrict__ g, const float* __restrict__ be, uint32_t* __restrict__ slrp) {
  __shared__ float xb9[4][8 * 12];
  __shared__ float hb[4][8 * 128];
  int w = threadIdx.x >> 6, l = threadIdx.x & 63;
  int base = blockIdx.x * 16 + w * 4;  // 4 edges, rows 0..3 = sf, rows 4..7 = rf
  if (l < 8) {
    int e = base + (l & 3);
    bool isR = l >= 4;
    const float* p0 = isR ? rvt : svt;
    const float* p1 = isR ? rvtm1 : svtm1;
    const float* p2 = isR ? rwt : swt;
    float sgn = isR ? -1.f : 1.f;
    float ax = va[e * 3], ay = va[e * 3 + 1], az = va[e * 3 + 2];
    float bx = vb[e * 3], by = vb[e * 3 + 1], bz = vb[e * 3 + 2];
    float cx = vc[e * 3], cy = vc[e * 3 + 1], cz = vc[e * 3 + 2];
    const float* ps[3] = {p0, p1, p2};
#pragma unroll
    for (int q = 0; q < 3; ++q) {
      float vx = ps[q][e * 3], vy = ps[q][e * 3 + 1], vz = ps[q][e * 3 + 2];
      xb9[w][l * 12 + q * 3 + 0] = sgn * (vx * ax + vy * ay + vz * az);
      xb9[w][l * 12 + q * 3 + 1] = sgn * (vx * bx + vy * by + vz * bz);
      xb9[w][l * 12 + q * 3 + 2] = sgn * (vx * cx + vy * cy + vz * cz);
    }
  }
  __syncthreads();
  float b10 = b1[l], b11 = b1[l + 64];
  float a0[8], a1[8];
#pragma unroll
  for (int r = 0; r < 8; ++r) { a0[r] = b10; a1[r] = b11; }
#pragma unroll
  for (int i = 0; i < 9; ++i) {
    float w0 = W1[i * 128 + l], w1 = W1[i * 128 + 64 + l];
#pragma unroll
    for (int r = 0; r < 8; ++r) {
      float xv = xb9[w][r * 12 + i];
      a0[r] = fmaf(xv, w0, a0[r]);
      a1[r] = fmaf(xv, w1, a1[r]);
    }
  }
#pragma unroll
  for (int r = 0; r < 8; ++r) {
    hb[w][r * 128 + l] = fmaxf(a0[r], 0.f);
    hb[w][r * 128 + 64 + l] = fmaxf(a1[r], 0.f);
  }
  __syncthreads();
  float y0[8], y1[8];
  float b20 = b2[l], b21 = b2[l + 64];
#pragma unroll
  for (int r = 0; r < 8; ++r) { y0[r] = b20; y1[r] = b21; }
  gemv8(W2, hb[w], 128, 128, l, y0, y1);
  layernorm8(y0, y1, g[l], g[l + 64], be[l], be[l + 64]);
#pragma unroll
  for (int r = 0; r < 4; ++r) {
    float s0 = y0[r] + y0[r + 4];
    float s1 = y1[r] + y1[r + 4];
    slrp[(size_t)(base + r) * 64 + l] = f2bf16(s0) | (f2bf16(s1) << 16);
  }
}

// ---------------- prep: pack weights into bf16 MFMA frag order ----------------
// ie W1P: ushort[ks<12][c<128][kin<32]; X col order kx: [0,128) slr-interleaved, [128,384) identity.
// ie W2P: ushort[ks<4][c<128][kin<32].
// dec W1D (W1cat = [i1_W1|i2_W1|fs_W1]): ushort[ks<4][c<384][kin<32]; K=128 identity order.
// dec W2D (W2cat [384 x 16]: cols 0-2 i1_W2, 3-5 i2_W2, 6 fs_W2, rest 0): ushort[ks<12][col<16][kin<32].
__global__ __launch_bounds__(256) void k_prep(
    const float* __restrict__ W1, const float* __restrict__ W2,
    const float* __restrict__ i1W1, const float* __restrict__ i2W1,
    const float* __restrict__ fsW1,
    const float* __restrict__ i1W2, const float* __restrict__ i2W2,
    const float* __restrict__ fsW2,
    unsigned short* __restrict__ W1P, unsigned short* __restrict__ W2P,
    unsigned short* __restrict__ W1D, unsigned short* __restrict__ W2D) {
  int i = blockIdx.x * 256 + threadIdx.x;   // grid covers 49152
  if (i < 12 * 128 * 32) {
    int kin = i & 31, c = (i >> 5) & 127, ks = i >> 12;
    int kx = ks * 32 + kin;
    int ko = (kx < 128) ? ((kx & 1) * 64 + (kx >> 1)) : kx;
    W1P[i] = (unsigned short)f2bf16(W1[(size_t)ko * 128 + c]);
  }
  if (i < 4 * 128 * 32) {
    int kin = i & 31, c = (i >> 5) & 127, ks = i >> 12;
    W2P[i] = (unsigned short)f2bf16(W2[(size_t)(ks * 32 + kin) * 128 + c]);
  }
  if (i < 4 * 384 * 32) {
    int kin = i & 31;
    int rest = i >> 5;
    int c = rest % 384;
    int ks = rest / 384;
    int k = ks * 32 + kin;
    int head = c >> 7, ch = c & 127;
    const float* Wh = head == 0 ? i1W1 : head == 1 ? i2W1 : fsW1;
    W1D[i] = (unsigned short)f2bf16(Wh[(size_t)k * 128 + ch]);
  }
  if (i < 12 * 16 * 32) {
    int kin = i & 31;
    int rest = i >> 5;
    int col = rest & 15;
    int ks = rest >> 4;
    int k = ks * 32 + kin;
    float v = 0.f;
    if (k < 128) { if (col < 3) v = i1W2[(size_t)k * 3 + col]; }
    else if (k < 256) { if (col >= 3 && col < 6) v = i2W2[(size_t)(k - 128) * 3 + (col - 3)]; }
    else { if (col == 6) v = fsW2[k - 256]; }
    W2D[i] = (unsigned short)f2bf16(v);
  }
}

// ---------------- interaction encoder (ie): MFMA bf16, 384 -> 128 -> 128, LN ----------------
// 64 edges/block, 4 waves; wave w owns output cols [w*32, w*32+32).
// LDS: X bf16 [64][384] swizzled (49152 B) ; H bf16 [64][128] swizzled (16384 B) = 65536 B.
// Y fp32 [64][132] reuses the X region after the H barrier.
// Swizzle: byte ^= (row&7)<<4 — row pitches (768B / 256B) are 0 mod 128 banks, which would be
// a 16-way conflict on the ds_read_b128 A-frag loads (G4 / T2); XOR spreads 8 rows over 8 slots.
__global__ __launch_bounds__(256) void k_ie_mfma(
    const int* __restrict__ ei, const float* __restrict__ NL,
    const uint32_t* __restrict__ slrp,
    const unsigned short* __restrict__ W1P, const unsigned short* __restrict__ W2P,
    const float* __restrict__ b1, const float* __restrict__ b2,
    const float* __restrict__ g, const float* __restrict__ be,
    float* __restrict__ il) {
  __shared__ uint8_t lds[65536];
  int tid = threadIdx.x;
  int w = tid >> 6, l = tid & 63;
  int lrow = l & 15, lk = l >> 4;
  int base = blockIdx.x * 64;

  // edge indices once per block (H region doubles as scratch during staging)
  int* eis = (int*)(lds + 49152);
  int* eit = eis + 64;
  if (tid < 64) {
    eis[tid] = ei[base + tid];
    eit[tid] = ei[E_EDGES + base + tid];
  }
  __syncthreads();

  // ---- stage X (bf16, swizzled) ----
  // seg A: slr packed u32 -> X cols [0,128) (interleaved order, matched by W1P perm)
#pragma unroll
  for (int i = tid; i < 64 * 64; i += 256) {
    int r = i >> 6, c = i & 63;
    uint32_t bo = ((uint32_t)r * 768 + (uint32_t)c * 4) ^ ((uint32_t)(r & 7) << 4);
    *(uint32_t*)(lds + bo) = slrp[(size_t)(base + r) * 64 + c];
  }
  // seg B: NL[s]+NL[t] -> X cols [128,256)
  const float2* NL2 = (const float2*)NL;
#pragma unroll
  for (int i = tid; i < 64 * 64; i += 256) {
    int r = i >> 6, c = i & 63;
    float2 a = NL2[(size_t)eis[r] * 64 + c];
    float2 bq = NL2[(size_t)eit[r] * 64 + c];
    uint32_t p = f2bf16(a.x + bq.x) | (f2bf16(a.y + bq.y) << 16);
    uint32_t bo = ((uint32_t)r * 768 + 256u + (uint32_t)c * 4) ^ ((uint32_t)(r & 7) << 4);
    *(uint32_t*)(lds + bo) = p;
  }
  // seg C: e_lat -> X cols [256,384)
  const float2* IL2 = (const float2*)il;
#pragma unroll
  for (int i = tid; i < 64 * 64; i += 256) {
    int r = i >> 6, c = i & 63;
    float2 a = IL2[(size_t)(base + r) * 64 + c];
    uint32_t p = f2bf16(a.x) | (f2bf16(a.y) << 16);
    uint32_t bo = ((uint32_t)r * 768 + 512u + (uint32_t)c * 4) ^ ((uint32_t)(r & 7) << 4);
    *(uint32_t*)(lds + bo) = p;
  }

  // register-resident W2 frags + per-col biases (independent of staging)
  int wc = w * 32;
  bf16x8 w2f[4][2];
#pragma unroll
  for (int ks = 0; ks < 4; ++ks)
#pragma unroll
    for (int ct = 0; ct < 2; ++ct)
      w2f[ks][ct] = *(const bf16x8*)(W2P + ((size_t)(ks * 128 + wc + ct * 16 + lrow) * 32 + lk * 8));
  float b1c0 = b1[wc + lrow], b1c1 = b1[wc + 16 + lrow];
  float b2c0 = b2[wc + lrow], b2c1 = b2[wc + 16 + lrow];

  __syncthreads();

  // ---- GEMM1: 64 rows x 32 cols (per wave), K=384 ----
  f32x4 acc[4][2];
#pragma unroll
  for (int rt = 0; rt < 4; ++rt)
#pragma unroll
    for (int ct = 0; ct < 2; ++ct) acc[rt][ct] = (f32x4){0.f, 0.f, 0.f, 0.f};
#pragma unroll 2
  for (int ks = 0; ks < 12; ++ks) {
    bf16x8 bf0 = *(const bf16x8*)(W1P + ((size_t)(ks * 128 + wc + lrow) * 32 + lk * 8));
    bf16x8 bf1 = *(const bf16x8*)(W1P + ((size_t)(ks * 128 + wc + 16 + lrow) * 32 + lk * 8));
#pragma unroll
    for (int rt = 0; rt < 4; ++rt) {
      int row = rt * 16 + lrow;
      uint32_t bo = ((uint32_t)row * 768 + (uint32_t)(ks * 64 + lk * 16)) ^ ((uint32_t)(row & 7) << 4);
      bf16x8 af = *(const bf16x8*)(lds + bo);
      acc[rt][0] = __builtin_amdgcn_mfma_f32_16x16x32_bf16(af, bf0, acc[rt][0], 0, 0, 0);
      acc[rt][1] = __builtin_amdgcn_mfma_f32_16x16x32_bf16(af, bf1, acc[rt][1], 0, 0, 0);
    }
  }

  // ---- H = relu(acc + b1) -> bf16 LDS (swizzled) ----
  // D layout: col = lane&15, row = (lane>>4)*4 + q  [m89/m91 verified]
#pragma unroll
  for (int rt = 0; rt < 4; ++rt)
#pragma unroll
    for (int ct = 0; ct < 2; ++ct) {
      float bc = ct ? b1c1 : b1c0;
      int col = wc + ct * 16 + lrow;
#pragma unroll
      for (int q = 0; q < 4; ++q) {
        int row = rt * 16 + lk * 4 + q;
        float h = fmaxf(acc[rt][ct][q] + bc, 0.f);
        uint32_t bo = ((uint32_t)row * 256 + (uint32_t)col * 2) ^ ((uint32_t)(row & 7) << 4);
        *(unsigned short*)(lds + 49152 + bo) = (unsigned short)f2bf16(h);
      }
    }
  __syncthreads();

  // ---- GEMM2: K=128 ----
  f32x4 acc2[4][2];
#pragma unroll
  for (int rt = 0; rt < 4; ++rt)
#pragma unroll
    for (int ct = 0; ct < 2; ++ct) acc2[rt][ct] = (f32x4){0.f, 0.f, 0.f, 0.f};
#pragma unroll
  for (int ks = 0; ks < 4; ++ks) {
#pragma unroll
    for (int rt = 0; rt < 4; ++rt) {
      int row = rt * 16 + lrow;
      uint32_t bo = ((uint32_t)row * 256 + (uint32_t)(ks * 64 + lk * 16)) ^ ((uint32_t)(row & 7) << 4);
      bf16x8 af = *(const bf16x8*)(lds + 49152 + bo);
      acc2[rt][0] = __builtin_amdgcn_mfma_f32_16x16x32_bf16(af, w2f[ks][0], acc2[rt][0], 0, 0, 0);
      acc2[rt][1] = __builtin_amdgcn_mfma_f32_16x16x32_bf16(af, w2f[ks][1], acc2[rt][1], 0, 0, 0);
    }
  }

  // ---- Y = acc2 + b2 -> fp32 LDS (reuses X region; all X reads completed at the H barrier) ----
  float* Ys = (float*)lds;   // pitch 132 floats (132 % 32 == 4 -> write groups spread, G4)
#pragma unroll
  for (int rt = 0; rt < 4; ++rt)
#pragma unroll
    for (int ct = 0; ct < 2; ++ct) {
      float bc = ct ? b2c1 : b2c0;
      int col = wc + ct * 16 + lrow;
#pragma unroll
      for (int q = 0; q < 4; ++q) {
        int row = rt * 16 + lk * 4 + q;
        Ys[row * 132 + col] = acc2[rt][ct][q] + bc;
      }
    }
  __syncthreads();

  // ---- LayerNorm (wave-parallel, 16 rows/wave) + store ----
  float gl0 = g[l], gl1 = g[l + 64], bl0 = be[l], bl1 = be[l + 64];
#pragma unroll
  for (int r16 = 0; r16 < 16; ++r16) {
    int row = w * 16 + r16;
    float y0 = Ys[row * 132 + l], y1 = Ys[row * 132 + 64 + l];
    float s = wave_sum64(y0 + y1);
    float s2 = wave_sum64(y0 * y0 + y1 * y1);
    float mu = s * 0.0078125f;
    float var = s2 * 0.0078125f - mu * mu;
    float rstd = rsqrtf(var + 1e-5f);
    size_t o = (size_t)(base + row) * 128;
    il[o + l] = (y0 - mu) * rstd * gl0 + bl0;
    il[o + 64 + l] = (y1 - mu) * rstd * gl1 + bl1;
  }
}

// ---------------- decoder heads via MFMA + physics + scatter ----------------
// 64 edges/block, 4 waves. GEMM1: H[64,384] = relu(X[64,128] @ W1cat + b1cat), wave w owns
// H-cols [w*96, w*96+96). GEMM2: Y[64,16] = H @ W2cat (cols 0-2 cf, 3-5 ca, 6 lam), wave w
// owns rows [w*16, w*16+16). Then 64 threads do per-edge physics + atomics.
// LDS: H bf16 [64][384] swizzled at 0 (49152 B); X bf16 [64][128] swizzled at 49152 (16384 B).
// Y fp32 [64][17] reuses the X region after the H barrier (all X reads precede it).
__global__ __launch_bounds__(256) void k_dec_mfma(
    const int* __restrict__ ei, const float* __restrict__ il,
    const unsigned short* __restrict__ W1D, const unsigned short* __restrict__ W2D,
    const float* __restrict__ i1b1, const float* __restrict__ i2b1,
    const float* __restrict__ fsb1,
    const float* __restrict__ i1b2, const float* __restrict__ i2b2,
    const float* __restrict__ fsb2,
    const float* __restrict__ nw, const float* __restrict__ spos, const float* __restrict__ rpos,
    const float* __restrict__ va, const float* __restrict__ vb, const float* __restrict__ vc,
    float* __restrict__ fsum, float* __restrict__ tsum) {
  __shared__ uint8_t lds[65536];
  int tid = threadIdx.x;
  int w = tid >> 6, l = tid & 63;
  int lrow = l & 15, lk = l >> 4;
  int base = blockIdx.x * 64;

  // ---- stage X = il (bf16, swizzled, pitch 256B) ----
  const float2* IL2 = (const float2*)il;
#pragma unroll
  for (int i = tid; i < 64 * 64; i += 256) {
    int r = i >> 6, c = i & 63;
    float2 a = IL2[(size_t)(base + r) * 64 + c];
    uint32_t p = f2bf16(a.x) | (f2bf16(a.y) << 16);
    uint32_t bo = ((uint32_t)r * 256 + (uint32_t)c * 4) ^ ((uint32_t)(r & 7) << 4);
    *(uint32_t*)(lds + 49152 + bo) = p;
  }

  // per-wave H-col biases: col = w*96 + ct*16 + lrow; b1cat by head = col>>7
  float b1c[6];
#pragma unroll
  for (int ct = 0; ct < 6; ++ct) {
    int c = w * 96 + ct * 16 + lrow;
    const float* bsel = (c < 128) ? i1b1 : (c < 256) ? i2b1 : fsb1;
    b1c[ct] = bsel[c & 127];
  }
  // W2 frags (B-operand, cols = lrow of 16) + output bias
  bf16x8 w2f[12];
#pragma unroll
  for (int ks = 0; ks < 12; ++ks)
    w2f[ks] = *(const bf16x8*)(W2D + ((size_t)(ks * 16 + lrow) * 32 + lk * 8));
  float b2c = lrow < 3 ? i1b2[lrow] : lrow < 6 ? i2b2[lrow - 3] : lrow == 6 ? fsb2[0] : 0.f;
  __syncthreads();

  // ---- GEMM1: 64 rows x 96 cols (per wave), K=128 ----
  f32x4 acc[4][6];
#pragma unroll
  for (int rt = 0; rt < 4; ++rt)
#pragma unroll
    for (int ct = 0; ct < 6; ++ct) acc[rt][ct] = (f32x4){0.f, 0.f, 0.f, 0.f};
#pragma unroll
  for (int ks = 0; ks < 4; ++ks) {
    bf16x8 bf[6];
#pragma unroll
    for (int ct = 0; ct < 6; ++ct)
      bf[ct] = *(const bf16x8*)(W1D + ((size_t)(ks * 384 + w * 96 + ct * 16 + lrow) * 32 + lk * 8));
#pragma unroll
    for (int rt = 0; rt < 4; ++rt) {
      int row = rt * 16 + lrow;
      uint32_t bo = ((uint32_t)row * 256 + (uint32_t)(ks * 64 + lk * 16)) ^ ((uint32_t)(row & 7) << 4);
      bf16x8 af = *(const bf16x8*)(lds + 49152 + bo);
#pragma unroll
      for (int ct = 0; ct < 6; ++ct)
        acc[rt][ct] = __builtin_amdgcn_mfma_f32_16x16x32_bf16(af, bf[ct], acc[rt][ct], 0, 0, 0);
    }
  }

  // ---- H = relu(acc + b1) -> bf16 LDS (swizzled, pitch 768B) ----
#pragma unroll
  for (int rt = 0; rt < 4; ++rt)
#pragma unroll
    for (int ct = 0; ct < 6; ++ct) {
      int col = w * 96 + ct * 16 + lrow;
#pragma unroll
      for (int q = 0; q < 4; ++q) {
        int row = rt * 16 + lk * 4 + q;
        float h = fmaxf(acc[rt][ct][q] + b1c[ct], 0.f);
        uint32_t bo = ((uint32_t)row * 768 + (uint32_t)col * 2) ^ ((uint32_t)(row & 7) << 4);
        *(unsigned short*)(lds + bo) = (unsigned short)f2bf16(h);
      }
    }
  __syncthreads();

  // ---- GEMM2: Y[16 rows (this wave) x 16 cols] = H @ W2cat, K=384 ----
  f32x4 acc2 = (f32x4){0.f, 0.f, 0.f, 0.f};
#pragma unroll
  for (int ks = 0; ks < 12; ++ks) {
    int row = w * 16 + lrow;
    uint32_t bo = ((uint32_t)row * 768 + (uint32_t)(ks * 64 + lk * 16)) ^ ((uint32_t)(row & 7) << 4);
    bf16x8 af = *(const bf16x8*)(lds + bo);
    acc2 = __builtin_amdgcn_mfma_f32_16x16x32_bf16(af, w2f[ks], acc2, 0, 0, 0);
  }

  // ---- Y -> fp32 LDS (reuses X region) ----
  float* Ys = (float*)(lds + 49152);  // [64][17]
#pragma unroll
  for (int q = 0; q < 4; ++q) {
    int row = w * 16 + lk * 4 + q;
    Ys[row * 17 + lrow] = acc2[q] + b2c;
  }
  __syncthreads();

  // ---- physics + scatter: one edge per thread ----
  if (tid < 64) {
    int e = base + tid;
    int s = ei[e], t = ei[E_EDGES + e];
    float cf0 = Ys[tid * 17 + 0], cf1 = Ys[tid * 17 + 1], cf2 = Ys[tid * 17 + 2];
    float ca0 = Ys[tid * 17 + 3], ca1 = Ys[tid * 17 + 4], ca2 = Ys[tid * 17 + 5];
    float lam = Ys[tid * 17 + 6];
    float ax = va[e * 3], ay = va[e * 3 + 1], az = va[e * 3 + 2];
    float bx = vb[e * 3], by = vb[e * 3 + 1], bz = vb[e * 3 + 2];
    float cx = vc[e * 3], cy = vc[e * 3 + 1], cz = vc[e * 3 + 2];
    float fx = cf0 * ax + cf1 * bx + cf2 * cx;
    float fy = cf0 * ay + cf1 * by + cf2 * cy;
    float fz = cf0 * az + cf1 * bz + cf2 * cz;
    float gx = ca0 * ax + ca1 * bx + ca2 * cx;
    float gy = ca0 * ay + ca1 * by + ca2 * cy;
    float gz = ca0 * az + ca1 * bz + ca2 * cz;
    float wsn = nw[s], wrn = nw[t];
    float sx = spos[e * 3], sy = spos[e * 3 + 1], sz = spos[e * 3 + 2];
    float rx = rpos[e * 3], ry = rpos[e * 3 + 1], rz = rpos[e * 3 + 2];
    float inv = 1.f / (wsn + wrn);
    float r0x = (wsn * sx + wrn * rx) * inv;
    float r0y = (wsn * sy + wrn * ry) * inv;
    float r0z = (wsn * sz + wrn * rz) * inv;
    float ddx = rx - r0x, ddy = ry - r0y, ddz = rz - r0z;
    float cxx = ddy * fz - ddz * fy;
    float cyy = ddz * fx - ddx * fz;
    float czz = ddx * fy - ddy * fx;
    float tx = gx - cxx * lam, ty = gy - cyy * lam, tz = gz - czz * lam;
    atomicAdd(&fsum[(size_t)t * 3 + 0], fx);
    atomicAdd(&fsum[(size_t)t * 3 + 1], fy);
    atomicAdd(&fsum[(size_t)t * 3 + 2], fz);
    atomicAdd(&tsum[(size_t)t * 3 + 0], tx);
    atomicAdd(&tsum[(size_t)t * 3 + 1], ty);
    atomicAdd(&tsum[(size_t)t * 3 + 2], tz);
  }
}

// ---------------- final node combine ----------------
__global__ __launch_bounds__(256) void k_final(const float* __restrict__ mi,
                                               const float* __restrict__ ii,
                                               const float* __restrict__ de,
                                               const float* __restrict__ fsum,
                                               const float* __restrict__ tsum,
                                               float* __restrict__ out) {
  int n = blockIdx.x * 256 + threadIdx.x;
  if (n >= N_NODES) return;
  float m = mi[n], iv = ii[n], d = de[n];
#pragma unroll
  for (int c = 0; c < 3; ++c) {
    out[(size_t)n * 3 + c] = m * fsum[(size_t)n * 3 + c] + d;
    out[(size_t)3 * N_NODES + (size_t)n * 3 + c] = iv * tsum[(size_t)n * 3 + c];
  }
}

// ---------------- launch ----------------
extern "C" void kernel_launch(void* const* d_in, const int* in_sizes, int n_in, void* d_out,
                              int out_size, void* d_ws, size_t ws_size, hipStream_t stream) {
  if (ws_size < WSEND) return;  // insufficient scratch; bail (will show as wrong output)

  const int* ei = (const int*)d_in[0];
  const float* spos = (const float*)d_in[1];
  const float* rpos = (const float*)d_in[2];
  const float* dx = (const float*)d_in[3];
  const float* dt = (const float*)d_in[4];
  const float* va = (const float*)d_in[5];
  const float* vb = (const float*)d_in[6];
  const float* vc = (const float*)d_in[7];
  const float* svt = (const float*)d_in[8];
  const float* svtm1 = (const float*)d_in[9];
  const float* swt = (const float*)d_in[10];
  const float* rvt = (const float*)d_in[11];
  const float* rvtm1 = (const float*)d_in[12];
  const float* rwt = (const float*)d_in[13];
  const float* attr = (const float*)d_in[14];
  const float* NL = (const float*)d_in[15];
  const float* ef_W1 = (const float*)d_in[16];
  const float* ef_b1 = (const float*)d_in[17];
  const float* ef_W2 = (const float*)d_in[18];
  const float* ef_b2 = (const float*)d_in[19];
  const float* ef_g = (const float*)d_in[20];
  const float* ef_b = (const float*)d_in[21];
  const float* ee_W1 = (const float*)d_in[22];
  const float* ee_b1 = (const float*)d_in[23];
  const float* ee_W2 = (const float*)d_in[24];
  const float* ee_b2 = (const float*)d_in[25];
  const float* ee_g = (const float*)d_in[26];
  const float* ee_b = (const float*)d_in[27];
  const float* ie_W1 = (const float*)d_in[28];
  const float* ie_b1 = (const float*)d_in[29];
  const float* ie_W2 = (const float*)d_in[30];
  const float* ie_b2 = (const float*)d_in[31];
  const float* ie_g = (const float*)d_in[32];
  const float* ie_b = (const float*)d_in[33];
  const float* i1_W1 = (const float*)d_in[34];
  const float* i1_b1 = (const float*)d_in[35];
  const float* i1_W2 = (const float*)d_in[36];
  const float* i1_b2 = (const float*)d_in[37];
  const float* i2_W1 = (const float*)d_in[38];
  const float* i2_b1 = (const float*)d_in[39];
  const float* i2_W2 = (const float*)d_in[40];
  const float* i2_b2 = (const float*)d_in[41];
  const float* fs_W1 = (const float*)d_in[42];
  const float* fs_b1 = (const float*)d_in[43];
  const float* fs_W2 = (const float*)d_in[44];
  const float* fs_b2 = (const float*)d_in[45];
  const float* nw_W1 = (const float*)d_in[46];
  const float* nw_b1 = (const float*)d_in[47];
  const float* nw_W2 = (const float*)d_in[48];
  const float* nw_b2 = (const float*)d_in[49];
  const float* mi_W1 = (const float*)d_in[50];
  const float* mi_b1 = (const float*)d_in[51];
  const float* mi_W2 = (const float*)d_in[52];
  const float* mi_b2 = (const float*)d_in[53];
  const float* ii_W1 = (const float*)d_in[54];
  const float* ii_b1 = (const float*)d_in[55];
  const float* ii_W2 = (const float*)d_in[56];
  const float* ii_b2 = (const float*)d_in[57];
  const float* de_W1 = (const float*)d_in[58];
  const float* de_b1 = (const float*)d_in[59];
  const float* de_W2 = (const float*)d_in[60];
  const float* de_b2 = (const float*)d_in[61];

  float* out = (float*)d_out;
  char* ws = (char*)d_ws;
  unsigned short* W1P = (unsigned short*)(ws + OW1P);
  unsigned short* W2P = (unsigned short*)(ws + OW2P);
  unsigned short* W1D = (unsigned short*)(ws + OW1D);
  unsigned short* W2D = (unsigned short*)(ws + OW2D);
  uint32_t* slrp = (uint32_t*)(ws + OSLR);
  float* o_nw = (float*)(ws + ONW);
  float* o_mi = (float*)(ws + OMI);
  float* o_ii = (float*)(ws + OII);
  float* o_de = (float*)(ws + ODE);
  float* fsum = (float*)(ws + OFS);
  float* tsum = (float*)(ws + OTS);
  float* il = out + 6 * N_NODES;  // interaction_latent region (also e_lat temp)

  hipMemsetAsync(ws + OFS, 0, (size_t)N_NODES * 24, stream);  // fsum + tsum

  hipLaunchKernelGGL(k_prep, dim3(192), dim3(256), 0, stream, ie_W1, ie_W2,
                     i1_W1, i2_W1, fs_W1, i1_W2, i2_W2, fs_W2, W1P, W2P, W1D, W2D);

  hipLaunchKernelGGL(k_node, dim3(N_NODES / 32), dim3(256), 0, stream, NL,
                     nw_W1, nw_b1, nw_W2, nw_b2, mi_W1, mi_b1, mi_W2, mi_b2,
                     ii_W1, ii_b1, ii_W2, ii_b2, de_W1, de_b1, de_W2, de_b2,
                     o_nw, o_mi, o_ii, o_de);

  hipLaunchKernelGGL(k_ee, dim3(E_EDGES / 32), dim3(256), 0, stream, dx, dt, attr, ee_W1, ee_b1,
                     ee_W2, ee_b2, ee_g, ee_b, il);

  hipLaunchKernelGGL(k_ef, dim3(E_EDGES / 16), dim3(256), 0, stream, va, vb, vc, svt, svtm1, swt,
                     rvt, rvtm1, rwt, ef_W1, ef_b1, ef_W2, ef_b2, ef_g, ef_b, slrp);

  hipLaunchKernelGGL(k_ie_mfma, dim3(E_EDGES / 64), dim3(256), 0, stream, ei, NL, slrp,
                     W1P, W2P, ie_b1, ie_b2, ie_g, ie_b, il);

  hipLaunchKernelGGL(k_dec_mfma, dim3(E_EDGES / 64), dim3(256), 0, stream, ei, il,
                     W1D, W2D, i1_b1, i2_b1, fs_b1, i1_b2, i2_b2, fs_b2,
                     o_nw, spos, rpos, va, vb, vc, fsum, tsum);

  hipLaunchKernelGGL(k_final, dim3((N_NODES + 255) / 256), dim3(256), 0, stream, o_mi, o_ii, o_de,
                     fsum, tsum, out);
}

// Round 3
// 1420.560 us; speedup vs baseline: 2.0739x; 1.2970x over previous
//
#include <hip/hip_runtime.h>
#include <hip/hip_fp16.h>
#include <stdint.h>

#define E_EDGES 400000
#define N_NODES 100000

// ---------------- workspace layout (bytes) ----------------
#define OW1P  ((size_t)0)                              // ushort[12*128*32] ie_W1 packed fp16 frag-order
#define OW2P  ((size_t)98304)                          // ushort[4*128*32]  ie_W2 packed fp16
#define OW1D  ((size_t)131072)                         // ushort[4*384*32]  dec W1cat packed fp16
#define OW2D  ((size_t)229376)                         // ushort[12*16*32]  dec W2cat packed fp16
#define OW1E  ((size_t)241664)                         // ushort[128*32]    ef_W1 packed (K 9->32 pad)
#define OW2E  ((size_t)249856)                         // ushort[4*128*32]  ef_W2 packed
#define OW1C  ((size_t)282624)                         // ushort[128*32]    ee_W1 packed (K 3->32 pad)
#define OW2C  ((size_t)290816)                         // ushort[4*128*32]  ee_W2 packed
#define OSLR  ((size_t)524288)                         // slr packed fp16, u32[E*64]
#define ONW   (OSLR + (size_t)E_EDGES * 64 * 4)        // float[N]  node_weights
#define OMI   (ONW + (size_t)N_NODES * 4)              // float[N]  m_inv
#define OII   (OMI + (size_t)N_NODES * 4)              // float[N]  i_inv
#define ODE   (OII + (size_t)N_NODES * 4)              // float[N]  de_out
#define OFS   (ODE + (size_t)N_NODES * 4)              // float[3N] fij sums
#define OTS   (OFS + (size_t)N_NODES * 12)             // float[3N] tau sums
#define WSEND (OTS + (size_t)N_NODES * 12)

typedef __attribute__((ext_vector_type(8))) _Float16 f16x8;
typedef __attribute__((ext_vector_type(4))) float f32x4;

// ---------------- helpers ----------------
__device__ __forceinline__ uint32_t f2h(float f) {
  return (uint32_t)__half_as_ushort(__float2half(f));   // RNE
}
__device__ __forceinline__ float wave_sum64(float v) {
#pragma unroll
  for (int off = 32; off > 0; off >>= 1) v += __shfl_xor(v, off, 64);
  return v;
}

// acc[8] pairs: a0 -> out col = lane, a1 -> out col = lane+64.
__device__ __forceinline__ void gemv8(const float* __restrict__ W,
                                      const float* __restrict__ xb, int xstride,
                                      int Ka, int lane, float* a0, float* a1) {
#pragma unroll 2
  for (int i = 0; i < Ka; i += 4) {
    float w0[4], w1[4];
#pragma unroll
    for (int u = 0; u < 4; ++u) {
      w0[u] = W[(size_t)(i + u) * 128 + lane];
      w1[u] = W[(size_t)(i + u) * 128 + 64 + lane];
    }
#pragma unroll
    for (int r = 0; r < 8; ++r) {
#pragma unroll
      for (int u = 0; u < 4; ++u) {
        float xv = xb[r * xstride + i + u];
        a0[r] = fmaf(xv, w0[u], a0[r]);
        a1[r] = fmaf(xv, w1[u], a1[r]);
      }
    }
  }
}

// copy 8 contiguous rows of 128 floats (4KB) global -> LDS, one wave
__device__ __forceinline__ void copy8x128(const float* __restrict__ src,
                                          float* __restrict__ dst, int lane) {
#pragma unroll
  for (int t = 0; t < 4; ++t) {
    float4 v = ((const float4*)src)[lane + 64 * t];
    ((float4*)dst)[lane + 64 * t] = v;
  }
}

// ---------------- node MLPs: nw, mi, ii, de (128->128->1), full fp32 ----------------
__global__ __launch_bounds__(256) void k_node(
    const float* __restrict__ NL,
    const float* __restrict__ nw_W1, const float* __restrict__ nw_b1,
    const float* __restrict__ nw_W2, const float* __restrict__ nw_b2,
    const float* __restrict__ mi_W1, const float* __restrict__ mi_b1,
    const float* __restrict__ mi_W2, const float* __restrict__ mi_b2,
    const float* __restrict__ ii_W1, const float* __restrict__ ii_b1,
    const float* __restrict__ ii_W2, const float* __restrict__ ii_b2,
    const float* __restrict__ de_W1, const float* __restrict__ de_b1,
    const float* __restrict__ de_W2, const float* __restrict__ de_b2,
    float* __restrict__ o_nw, float* __restrict__ o_mi, float* __restrict__ o_ii,
    float* __restrict__ o_de) {
  __shared__ float xb[4][8 * 128];
  int w = threadIdx.x >> 6, l = threadIdx.x & 63;
  int nb = blockIdx.x * 32 + w * 8;
  copy8x128(NL + (size_t)nb * 128, xb[w], l);
  __syncthreads();
  const float* W1s[4] = {nw_W1, mi_W1, ii_W1, de_W1};
  const float* B1[4] = {nw_b1, mi_b1, ii_b1, de_b1};
  const float* W2[4] = {nw_W2, mi_W2, ii_W2, de_W2};
  const float* B2[4] = {nw_b2, mi_b2, ii_b2, de_b2};
  float* OUT[4] = {o_nw, o_mi, o_ii, o_de};
#pragma unroll
  for (int m = 0; m < 4; ++m) {
    float b10 = B1[m][l], b11 = B1[m][l + 64];
    float a0[8], a1[8];
#pragma unroll
    for (int r = 0; r < 8; ++r) { a0[r] = b10; a1[r] = b11; }
    gemv8(W1s[m], xb[w], 128, 128, l, a0, a1);
    float w2a = W2[m][l], w2b = W2[m][l + 64];
    float b2 = B2[m][0];
    float y[8];
#pragma unroll
    for (int r = 0; r < 8; ++r) {
      float p = fmaxf(a0[r], 0.f) * w2a + fmaxf(a1[r], 0.f) * w2b;
      y[r] = wave_sum64(p) + b2;
    }
    if (l == 0) {
#pragma unroll
      for (int r = 0; r < 8; ++r) OUT[m][nb + r] = y[r];
    }
  }
}

// ---------------- prep: pack all MLP weights into fp16 MFMA frag order ----------------
// frag layout convention (proven in k_ie_mfma): W[ks][c][kin] as ushort, lane reads 8 fp16 at
// ((ks*COLS + c)*32 + lk*8).
__global__ __launch_bounds__(256) void k_prep(
    const float* __restrict__ W1, const float* __restrict__ W2,
    const float* __restrict__ i1W1, const float* __restrict__ i2W1,
    const float* __restrict__ fsW1,
    const float* __restrict__ i1W2, const float* __restrict__ i2W2,
    const float* __restrict__ fsW2,
    const float* __restrict__ efW1, const float* __restrict__ efW2,
    const float* __restrict__ eeW1, const float* __restrict__ eeW2,
    unsigned short* __restrict__ W1P, unsigned short* __restrict__ W2P,
    unsigned short* __restrict__ W1D, unsigned short* __restrict__ W2D,
    unsigned short* __restrict__ W1E, unsigned short* __restrict__ W2E,
    unsigned short* __restrict__ W1C, unsigned short* __restrict__ W2C) {
  int i = blockIdx.x * 256 + threadIdx.x;   // grid covers 49152
  if (i < 12 * 128 * 32) {                  // ie W1 (X col perm: [0,128) slr-interleaved)
    int kin = i & 31, c = (i >> 5) & 127, ks = i >> 12;
    int kx = ks * 32 + kin;
    int ko = (kx < 128) ? ((kx & 1) * 64 + (kx >> 1)) : kx;
    W1P[i] = (unsigned short)f2h(W1[(size_t)ko * 128 + c]);
  }
  if (i < 4 * 128 * 32) {                   // ie W2
    int kin = i & 31, c = (i >> 5) & 127, ks = i >> 12;
    W2P[i] = (unsigned short)f2h(W2[(size_t)(ks * 32 + kin) * 128 + c]);
  }
  if (i < 4 * 384 * 32) {                   // dec W1cat = [i1|i2|fs]
    int kin = i & 31;
    int rest = i >> 5;
    int c = rest % 384;
    int ks = rest / 384;
    int k = ks * 32 + kin;
    int head = c >> 7, ch = c & 127;
    const float* Wh = head == 0 ? i1W1 : head == 1 ? i2W1 : fsW1;
    W1D[i] = (unsigned short)f2h(Wh[(size_t)k * 128 + ch]);
  }
  if (i < 12 * 16 * 32) {                   // dec W2cat [384 x 16]
    int kin = i & 31;
    int rest = i >> 5;
    int col = rest & 15;
    int ks = rest >> 4;
    int k = ks * 32 + kin;
    float v = 0.f;
    if (k < 128) { if (col < 3) v = i1W2[(size_t)k * 3 + col]; }
    else if (k < 256) { if (col >= 3 && col < 6) v = i2W2[(size_t)(k - 128) * 3 + (col - 3)]; }
    else { if (col == 6) v = fsW2[k - 256]; }
    W2D[i] = (unsigned short)f2h(v);
  }
  if (i < 128 * 32) {                       // ef W1 (9 real K rows, pad to 32)
    int kin = i & 31, c = i >> 5;
    W1E[i] = (unsigned short)(kin < 9 ? f2h(efW1[(size_t)kin * 128 + c]) : 0);
  }
  if (i < 4 * 128 * 32) {                   // ef W2
    int kin = i & 31, c = (i >> 5) & 127, ks = i >> 12;
    W2E[i] = (unsigned short)f2h(efW2[(size_t)(ks * 32 + kin) * 128 + c]);
  }
  if (i < 128 * 32) {                       // ee W1 (3 real K rows, pad to 32)
    int kin = i & 31, c = i >> 5;
    W1C[i] = (unsigned short)(kin < 3 ? f2h(eeW1[(size_t)kin * 128 + c]) : 0);
  }
  if (i < 4 * 128 * 32) {                   // ee W2
    int kin = i & 31, c = (i >> 5) & 127, ks = i >> 12;
    W2C[i] = (unsigned short)f2h(eeW2[(size_t)(ks * 32 + kin) * 128 + c]);
  }
}

// ===== shared MFMA-MLP skeleton pieces (LDS layout for ee/ef kernels) =====
// YOFF fp32 [64][132] = 33792 B; XOFF fp16 [64] rows, pitch 80 B (K=32) = 5120 B;
// HOFF fp16 [64][128] swizzled pitch 256 B = 16384 B. Total 55296 B -> 2 blocks/CU.
#define EF_YOFF 0
#define EF_XOFF 33792
#define EF_HOFF 38912
#define EF_LDS  55296

// GEMM1 (K=32, 1 ks) + ReLU->H + GEMM2 (K=128) + bias->Y. Wave w owns cols [w*32,w*32+32).
__device__ __forceinline__ void mlp32_128(uint8_t* lds, const unsigned short* W1f,
                                          const unsigned short* W2f,
                                          const float* b1, const float* b2,
                                          int w, int l) {
  int lrow = l & 15, lk = l >> 4;
  int wc = w * 32;
  // reg-resident W2 frags
  f16x8 w2f[4][2];
#pragma unroll
  for (int ks = 0; ks < 4; ++ks)
#pragma unroll
    for (int ct = 0; ct < 2; ++ct)
      w2f[ks][ct] = *(const f16x8*)(W2f + ((size_t)(ks * 128 + wc + ct * 16 + lrow) * 32 + lk * 8));
  float b1c0 = b1[wc + lrow], b1c1 = b1[wc + 16 + lrow];
  float b2c0 = b2[wc + lrow], b2c1 = b2[wc + 16 + lrow];
  f16x8 bf0 = *(const f16x8*)(W1f + ((size_t)(wc + lrow) * 32 + lk * 8));
  f16x8 bf1 = *(const f16x8*)(W1f + ((size_t)(wc + 16 + lrow) * 32 + lk * 8));

  __syncthreads();   // X staged

  // GEMM1: K=32 single step
  f32x4 acc[4][2];
#pragma unroll
  for (int rt = 0; rt < 4; ++rt) {
    int row = rt * 16 + lrow;
    f16x8 af = *(const f16x8*)(lds + EF_XOFF + (uint32_t)row * 80 + lk * 16);
    acc[rt][0] = __builtin_amdgcn_mfma_f32_16x16x32_f16(af, bf0, (f32x4){0.f,0.f,0.f,0.f}, 0, 0, 0);
    acc[rt][1] = __builtin_amdgcn_mfma_f32_16x16x32_f16(af, bf1, (f32x4){0.f,0.f,0.f,0.f}, 0, 0, 0);
  }
  // H = relu(acc+b1) -> fp16 LDS swizzled
#pragma unroll
  for (int rt = 0; rt < 4; ++rt)
#pragma unroll
    for (int ct = 0; ct < 2; ++ct) {
      float bc = ct ? b1c1 : b1c0;
      int col = wc + ct * 16 + lrow;
#pragma unroll
      for (int q = 0; q < 4; ++q) {
        int row = rt * 16 + lk * 4 + q;
        float h = fmaxf(acc[rt][ct][q] + bc, 0.f);
        uint32_t bo = ((uint32_t)row * 256 + (uint32_t)col * 2) ^ ((uint32_t)(row & 7) << 4);
        *(unsigned short*)(lds + EF_HOFF + bo) = (unsigned short)f2h(h);
      }
    }
  __syncthreads();

  // GEMM2: K=128
  f32x4 acc2[4][2];
#pragma unroll
  for (int rt = 0; rt < 4; ++rt)
#pragma unroll
    for (int ct = 0; ct < 2; ++ct) acc2[rt][ct] = (f32x4){0.f, 0.f, 0.f, 0.f};
#pragma unroll
  for (int ks = 0; ks < 4; ++ks) {
#pragma unroll
    for (int rt = 0; rt < 4; ++rt) {
      int row = rt * 16 + lrow;
      uint32_t bo = ((uint32_t)row * 256 + (uint32_t)(ks * 64 + lk * 16)) ^ ((uint32_t)(row & 7) << 4);
      f16x8 af = *(const f16x8*)(lds + EF_HOFF + bo);
      acc2[rt][0] = __builtin_amdgcn_mfma_f32_16x16x32_f16(af, w2f[ks][0], acc2[rt][0], 0, 0, 0);
      acc2[rt][1] = __builtin_amdgcn_mfma_f32_16x16x32_f16(af, w2f[ks][1], acc2[rt][1], 0, 0, 0);
    }
  }
  // Y = acc2 + b2 -> fp32 LDS (own region, no hazard)
  float* Ys = (float*)(lds + EF_YOFF);
#pragma unroll
  for (int rt = 0; rt < 4; ++rt)
#pragma unroll
    for (int ct = 0; ct < 2; ++ct) {
      float bc = ct ? b2c1 : b2c0;
      int col = wc + ct * 16 + lrow;
#pragma unroll
      for (int q = 0; q < 4; ++q) {
        int row = rt * 16 + lk * 4 + q;
        Ys[row * 132 + col] = acc2[rt][ct][q] + bc;
      }
    }
  __syncthreads();
}

// ---------------- edge encoder (ee): MFMA, [||dx||,||dt||,attr] -> 128 -> 128, LN ----------------
// 64 edges/block.
__global__ __launch_bounds__(256) void k_ee_mfma(
    const float* __restrict__ dx, const float* __restrict__ dt, const float* __restrict__ attr,
    const unsigned short* __restrict__ W1C, const unsigned short* __restrict__ W2C,
    const float* __restrict__ b1, const float* __restrict__ b2,
    const float* __restrict__ g, const float* __restrict__ be, float* __restrict__ elat) {
  __shared__ uint8_t lds[EF_LDS];
  int tid = threadIdx.x;
  int w = tid >> 6, l = tid & 63;
  int base = blockIdx.x * 64;

  if (tid < 64) {
    int e = base + tid;
    float a0 = dx[e * 3], a1v = dx[e * 3 + 1], a2 = dx[e * 3 + 2];
    float t0 = dt[e * 3], t1 = dt[e * 3 + 1], t2 = dt[e * 3 + 2];
    float f0 = sqrtf(a0 * a0 + a1v * a1v + a2 * a2);
    float f1 = sqrtf(t0 * t0 + t1 * t1 + t2 * t2);
    float f2v = attr[e];
    uint32_t* xr = (uint32_t*)(lds + EF_XOFF + (uint32_t)tid * 80);
    xr[0] = f2h(f0) | (f2h(f1) << 16);
    xr[1] = f2h(f2v);
#pragma unroll
    for (int j = 2; j < 16; ++j) xr[j] = 0;
  }

  mlp32_128(lds, W1C, W2C, b1, b2, w, l);

  // LN + store (wave handles 16 rows)
  float* Ys = (float*)(lds + EF_YOFF);
  float gl0 = g[l], gl1 = g[l + 64], bl0 = be[l], bl1 = be[l + 64];
#pragma unroll
  for (int r16 = 0; r16 < 16; ++r16) {
    int row = w * 16 + r16;
    float y0 = Ys[row * 132 + l], y1 = Ys[row * 132 + 64 + l];
    float s = wave_sum64(y0 + y1);
    float s2 = wave_sum64(y0 * y0 + y1 * y1);
    float mu = s * 0.0078125f;
    float var = s2 * 0.0078125f - mu * mu;
    float rstd = rsqrtf(var + 1e-5f);
    size_t o = (size_t)(base + row) * 128;
    elat[o + l] = (y0 - mu) * rstd * gl0 + bl0;
    elat[o + 64 + l] = (y1 - mu) * rstd * gl1 + bl1;
  }
}

// ---------------- edge-feature encoder (ef): MFMA, 9 -> 128 -> 128, LN; slr = s+r ----------------
// 32 edges/block -> 64 rows: row r<32 sender of edge base+r; row r>=32 receiver (negated feats).
__global__ __launch_bounds__(256) void k_ef_mfma(
    const float* __restrict__ va, const float* __restrict__ vb, const float* __restrict__ vc,
    const float* __restrict__ svt, const float* __restrict__ svtm1, const float* __restrict__ swt,
    const float* __restrict__ rvt, const float* __restrict__ rvtm1, const float* __restrict__ rwt,
    const unsigned short* __restrict__ W1E, const unsigned short* __restrict__ W2E,
    const float* __restrict__ b1, const float* __restrict__ b2,
    const float* __restrict__ g, const float* __restrict__ be, uint32_t* __restrict__ slrp) {
  __shared__ uint8_t lds[EF_LDS];
  int tid = threadIdx.x;
  int w = tid >> 6, l = tid & 63;
  int base = blockIdx.x * 32;

  if (tid < 64) {
    int row = tid;
    int e = base + (row & 31);
    bool isR = row >= 32;
    const float* p0 = isR ? rvt : svt;
    const float* p1 = isR ? rvtm1 : svtm1;
    const float* p2 = isR ? rwt : swt;
    float sgn = isR ? -1.f : 1.f;
    float ax = va[e * 3], ay = va[e * 3 + 1], az = va[e * 3 + 2];
    float bx = vb[e * 3], by = vb[e * 3 + 1], bz = vb[e * 3 + 2];
    float cx = vc[e * 3], cy = vc[e * 3 + 1], cz = vc[e * 3 + 2];
    float f[10];
    const float* ps[3] = {p0, p1, p2};
#pragma unroll
    for (int q = 0; q < 3; ++q) {
      float vx = ps[q][e * 3], vy = ps[q][e * 3 + 1], vz = ps[q][e * 3 + 2];
      f[q * 3 + 0] = sgn * (vx * ax + vy * ay + vz * az);
      f[q * 3 + 1] = sgn * (vx * bx + vy * by + vz * bz);
      f[q * 3 + 2] = sgn * (vx * cx + vy * cy + vz * cz);
    }
    f[9] = 0.f;
    uint32_t* xr = (uint32_t*)(lds + EF_XOFF + (uint32_t)row * 80);
#pragma unroll
    for (int j = 0; j < 5; ++j) xr[j] = f2h(f[2 * j]) | (f2h(f[2 * j + 1]) << 16);
#pragma unroll
    for (int j = 5; j < 16; ++j) xr[j] = 0;
  }

  mlp32_128(lds, W1E, W2E, b1, b2, w, l);

  // LN in-place (wave handles 16 rows), then combine sender+receiver
  float* Ys = (float*)(lds + EF_YOFF);
  float gl0 = g[l], gl1 = g[l + 64], bl0 = be[l], bl1 = be[l + 64];
#pragma unroll
  for (int r16 = 0; r16 < 16; ++r16) {
    int row = w * 16 + r16;
    float y0 = Ys[row * 132 + l], y1 = Ys[row * 132 + 64 + l];
    float s = wave_sum64(y0 + y1);
    float s2 = wave_sum64(y0 * y0 + y1 * y1);
    float mu = s * 0.0078125f;
    float var = s2 * 0.0078125f - mu * mu;
    float rstd = rsqrtf(var + 1e-5f);
    Ys[row * 132 + l] = (y0 - mu) * rstd * gl0 + bl0;
    Ys[row * 132 + 64 + l] = (y1 - mu) * rstd * gl1 + bl1;
  }
  __syncthreads();
  if (w < 2) {
#pragma unroll
    for (int r16 = 0; r16 < 16; ++r16) {
      int row = w * 16 + r16;
      float s0 = Ys[row * 132 + l] + Ys[(row + 32) * 132 + l];
      float s1 = Ys[row * 132 + 64 + l] + Ys[(row + 32) * 132 + 64 + l];
      slrp[(size_t)(base + row) * 64 + l] = f2h(s0) | (f2h(s1) << 16);
    }
  }
}

// ---------------- interaction encoder (ie): MFMA fp16, 384 -> 128 -> 128, LN ----------------
// 64 edges/block, 4 waves; wave w owns output cols [w*32, w*32+32).
// LDS: X fp16 [64][384] swizzled (49152 B) ; H fp16 [64][128] swizzled (16384 B) = 65536 B.
// Y fp32 [64][132] reuses the X region after the H barrier.
__global__ __launch_bounds__(256) void k_ie_mfma(
    const int* __restrict__ ei, const float* __restrict__ NL,
    const uint32_t* __restrict__ slrp,
    const unsigned short* __restrict__ W1P, const unsigned short* __restrict__ W2P,
    const float* __restrict__ b1, const float* __restrict__ b2,
    const float* __restrict__ g, const float* __restrict__ be,
    float* __restrict__ il) {
  __shared__ uint8_t lds[65536];
  int tid = threadIdx.x;
  int w = tid >> 6, l = tid & 63;
  int lrow = l & 15, lk = l >> 4;
  int base = blockIdx.x * 64;

  int* eis = (int*)(lds + 49152);
  int* eit = eis + 64;
  if (tid < 64) {
    eis[tid] = ei[base + tid];
    eit[tid] = ei[E_EDGES + base + tid];
  }
  __syncthreads();

  // seg A: slr packed u32 (fp16 pair) -> X cols [0,128) interleaved (matched by W1P perm)
#pragma unroll
  for (int i = tid; i < 64 * 64; i += 256) {
    int r = i >> 6, c = i & 63;
    uint32_t bo = ((uint32_t)r * 768 + (uint32_t)c * 4) ^ ((uint32_t)(r & 7) << 4);
    *(uint32_t*)(lds + bo) = slrp[(size_t)(base + r) * 64 + c];
  }
  // seg B: NL[s]+NL[t] -> X cols [128,256)
  const float2* NL2 = (const float2*)NL;
#pragma unroll
  for (int i = tid; i < 64 * 64; i += 256) {
    int r = i >> 6, c = i & 63;
    float2 a = NL2[(size_t)eis[r] * 64 + c];
    float2 bq = NL2[(size_t)eit[r] * 64 + c];
    uint32_t p = f2h(a.x + bq.x) | (f2h(a.y + bq.y) << 16);
    uint32_t bo = ((uint32_t)r * 768 + 256u + (uint32_t)c * 4) ^ ((uint32_t)(r & 7) << 4);
    *(uint32_t*)(lds + bo) = p;
  }
  // seg C: e_lat -> X cols [256,384)
  const float2* IL2 = (const float2*)il;
#pragma unroll
  for (int i = tid; i < 64 * 64; i += 256) {
    int r = i >> 6, c = i & 63;
    float2 a = IL2[(size_t)(base + r) * 64 + c];
    uint32_t p = f2h(a.x) | (f2h(a.y) << 16);
    uint32_t bo = ((uint32_t)r * 768 + 512u + (uint32_t)c * 4) ^ ((uint32_t)(r & 7) << 4);
    *(uint32_t*)(lds + bo) = p;
  }

  int wc = w * 32;
  f16x8 w2f[4][2];
#pragma unroll
  for (int ks = 0; ks < 4; ++ks)
#pragma unroll
    for (int ct = 0; ct < 2; ++ct)
      w2f[ks][ct] = *(const f16x8*)(W2P + ((size_t)(ks * 128 + wc + ct * 16 + lrow) * 32 + lk * 8));
  float b1c0 = b1[wc + lrow], b1c1 = b1[wc + 16 + lrow];
  float b2c0 = b2[wc + lrow], b2c1 = b2[wc + 16 + lrow];

  __syncthreads();

  // GEMM1: K=384
  f32x4 acc[4][2];
#pragma unroll
  for (int rt = 0; rt < 4; ++rt)
#pragma unroll
    for (int ct = 0; ct < 2; ++ct) acc[rt][ct] = (f32x4){0.f, 0.f, 0.f, 0.f};
#pragma unroll 2
  for (int ks = 0; ks < 12; ++ks) {
    f16x8 bf0 = *(const f16x8*)(W1P + ((size_t)(ks * 128 + wc + lrow) * 32 + lk * 8));
    f16x8 bf1 = *(const f16x8*)(W1P + ((size_t)(ks * 128 + wc + 16 + lrow) * 32 + lk * 8));
#pragma unroll
    for (int rt = 0; rt < 4; ++rt) {
      int row = rt * 16 + lrow;
      uint32_t bo = ((uint32_t)row * 768 + (uint32_t)(ks * 64 + lk * 16)) ^ ((uint32_t)(row & 7) << 4);
      f16x8 af = *(const f16x8*)(lds + bo);
      acc[rt][0] = __builtin_amdgcn_mfma_f32_16x16x32_f16(af, bf0, acc[rt][0], 0, 0, 0);
      acc[rt][1] = __builtin_amdgcn_mfma_f32_16x16x32_f16(af, bf1, acc[rt][1], 0, 0, 0);
    }
  }

  // H = relu(acc + b1) -> fp16 LDS (swizzled)
#pragma unroll
  for (int rt = 0; rt < 4; ++rt)
#pragma unroll
    for (int ct = 0; ct < 2; ++ct) {
      float bc = ct ? b1c1 : b1c0;
      int col = wc + ct * 16 + lrow;
#pragma unroll
      for (int q = 0; q < 4; ++q) {
        int row = rt * 16 + lk * 4 + q;
        float h = fmaxf(acc[rt][ct][q] + bc, 0.f);
        uint32_t bo = ((uint32_t)row * 256 + (uint32_t)col * 2) ^ ((uint32_t)(row & 7) << 4);
        *(unsigned short*)(lds + 49152 + bo) = (unsigned short)f2h(h);
      }
    }
  __syncthreads();

  // GEMM2: K=128
  f32x4 acc2[4][2];
#pragma unroll
  for (int rt = 0; rt < 4; ++rt)
#pragma unroll
    for (int ct = 0; ct < 2; ++ct) acc2[rt][ct] = (f32x4){0.f, 0.f, 0.f, 0.f};
#pragma unroll
  for (int ks = 0; ks < 4; ++ks) {
#pragma unroll
    for (int rt = 0; rt < 4; ++rt) {
      int row = rt * 16 + lrow;
      uint32_t bo = ((uint32_t)row * 256 + (uint32_t)(ks * 64 + lk * 16)) ^ ((uint32_t)(row & 7) << 4);
      f16x8 af = *(const f16x8*)(lds + 49152 + bo);
      acc2[rt][0] = __builtin_amdgcn_mfma_f32_16x16x32_f16(af, w2f[ks][0], acc2[rt][0], 0, 0, 0);
      acc2[rt][1] = __builtin_amdgcn_mfma_f32_16x16x32_f16(af, w2f[ks][1], acc2[rt][1], 0, 0, 0);
    }
  }

  // Y -> fp32 LDS (reuses X region; X reads all completed before H barrier)
  float* Ys = (float*)lds;
#pragma unroll
  for (int rt = 0; rt < 4; ++rt)
#pragma unroll
    for (int ct = 0; ct < 2; ++ct) {
      float bc = ct ? b2c1 : b2c0;
      int col = wc + ct * 16 + lrow;
#pragma unroll
      for (int q = 0; q < 4; ++q) {
        int row = rt * 16 + lk * 4 + q;
        Ys[row * 132 + col] = acc2[rt][ct][q] + bc;
      }
    }
  __syncthreads();

  float gl0 = g[l], gl1 = g[l + 64], bl0 = be[l], bl1 = be[l + 64];
#pragma unroll
  for (int r16 = 0; r16 < 16; ++r16) {
    int row = w * 16 + r16;
    float y0 = Ys[row * 132 + l], y1 = Ys[row * 132 + 64 + l];
    float s = wave_sum64(y0 + y1);
    float s2 = wave_sum64(y0 * y0 + y1 * y1);
    float mu = s * 0.0078125f;
    float var = s2 * 0.0078125f - mu * mu;
    float rstd = rsqrtf(var + 1e-5f);
    size_t o = (size_t)(base + row) * 128;
    il[o + l] = (y0 - mu) * rstd * gl0 + bl0;
    il[o + 64 + l] = (y1 - mu) * rstd * gl1 + bl1;
  }
}

// ---------------- decoder heads via MFMA + physics + scatter ----------------
__global__ __launch_bounds__(256) void k_dec_mfma(
    const int* __restrict__ ei, const float* __restrict__ il,
    const unsigned short* __restrict__ W1D, const unsigned short* __restrict__ W2D,
    const float* __restrict__ i1b1, const float* __restrict__ i2b1,
    const float* __restrict__ fsb1,
    const float* __restrict__ i1b2, const float* __restrict__ i2b2,
    const float* __restrict__ fsb2,
    const float* __restrict__ nw, const float* __restrict__ spos, const float* __restrict__ rpos,
    const float* __restrict__ va, const float* __restrict__ vb, const float* __restrict__ vc,
    float* __restrict__ fsum, float* __restrict__ tsum) {
  __shared__ uint8_t lds[65536];
  int tid = threadIdx.x;
  int w = tid >> 6, l = tid & 63;
  int lrow = l & 15, lk = l >> 4;
  int base = blockIdx.x * 64;

  // stage X = il (fp16, swizzled, pitch 256B)
  const float2* IL2 = (const float2*)il;
#pragma unroll
  for (int i = tid; i < 64 * 64; i += 256) {
    int r = i >> 6, c = i & 63;
    float2 a = IL2[(size_t)(base + r) * 64 + c];
    uint32_t p = f2h(a.x) | (f2h(a.y) << 16);
    uint32_t bo = ((uint32_t)r * 256 + (uint32_t)c * 4) ^ ((uint32_t)(r & 7) << 4);
    *(uint32_t*)(lds + 49152 + bo) = p;
  }

  float b1c[6];
#pragma unroll
  for (int ct = 0; ct < 6; ++ct) {
    int c = w * 96 + ct * 16 + lrow;
    const float* bsel = (c < 128) ? i1b1 : (c < 256) ? i2b1 : fsb1;
    b1c[ct] = bsel[c & 127];
  }
  f16x8 w2f[12];
#pragma unroll
  for (int ks = 0; ks < 12; ++ks)
    w2f[ks] = *(const f16x8*)(W2D + ((size_t)(ks * 16 + lrow) * 32 + lk * 8));
  float b2c = lrow < 3 ? i1b2[lrow] : lrow < 6 ? i2b2[lrow - 3] : lrow == 6 ? fsb2[0] : 0.f;
  __syncthreads();

  // GEMM1: 64x96 per wave, K=128
  f32x4 acc[4][6];
#pragma unroll
  for (int rt = 0; rt < 4; ++rt)
#pragma unroll
    for (int ct = 0; ct < 6; ++ct) acc[rt][ct] = (f32x4){0.f, 0.f, 0.f, 0.f};
#pragma unroll
  for (int ks = 0; ks < 4; ++ks) {
    f16x8 bf[6];
#pragma unroll
    for (int ct = 0; ct < 6; ++ct)
      bf[ct] = *(const f16x8*)(W1D + ((size_t)(ks * 384 + w * 96 + ct * 16 + lrow) * 32 + lk * 8));
#pragma unroll
    for (int rt = 0; rt < 4; ++rt) {
      int row = rt * 16 + lrow;
      uint32_t bo = ((uint32_t)row * 256 + (uint32_t)(ks * 64 + lk * 16)) ^ ((uint32_t)(row & 7) << 4);
      f16x8 af = *(const f16x8*)(lds + 49152 + bo);
#pragma unroll
      for (int ct = 0; ct < 6; ++ct)
        acc[rt][ct] = __builtin_amdgcn_mfma_f32_16x16x32_f16(af, bf[ct], acc[rt][ct], 0, 0, 0);
    }
  }

  // H = relu(acc + b1) -> fp16 LDS (swizzled, pitch 768B)
#pragma unroll
  for (int rt = 0; rt < 4; ++rt)
#pragma unroll
    for (int ct = 0; ct < 6; ++ct) {
      int col = w * 96 + ct * 16 + lrow;
#pragma unroll
      for (int q = 0; q < 4; ++q) {
        int row = rt * 16 + lk * 4 + q;
        float h = fmaxf(acc[rt][ct][q] + b1c[ct], 0.f);
        uint32_t bo = ((uint32_t)row * 768 + (uint32_t)col * 2) ^ ((uint32_t)(row & 7) << 4);
        *(unsigned short*)(lds + bo) = (unsigned short)f2h(h);
      }
    }
  __syncthreads();

  // GEMM2: Y[16 rows x 16 cols] per wave, K=384
  f32x4 acc2 = (f32x4){0.f, 0.f, 0.f, 0.f};
#pragma unroll
  for (int ks = 0; ks < 12; ++ks) {
    int row = w * 16 + lrow;
    uint32_t bo = ((uint32_t)row * 768 + (uint32_t)(ks * 64 + lk * 16)) ^ ((uint32_t)(row & 7) << 4);
    f16x8 af = *(const f16x8*)(lds + bo);
    acc2 = __builtin_amdgcn_mfma_f32_16x16x32_f16(af, w2f[ks], acc2, 0, 0, 0);
  }

  float* Ys = (float*)(lds + 49152);  // [64][17]
#pragma unroll
  for (int q = 0; q < 4; ++q) {
    int row = w * 16 + lk * 4 + q;
    Ys[row * 17 + lrow] = acc2[q] + b2c;
  }
  __syncthreads();

  if (tid < 64) {
    int e = base + tid;
    int s = ei[e], t = ei[E_EDGES + e];
    float cf0 = Ys[tid * 17 + 0], cf1 = Ys[tid * 17 + 1], cf2 = Ys[tid * 17 + 2];
    float ca0 = Ys[tid * 17 + 3], ca1 = Ys[tid * 17 + 4], ca2 = Ys[tid * 17 + 5];
    float lam = Ys[tid * 17 + 6];
    float ax = va[e * 3], ay = va[e * 3 + 1], az = va[e * 3 + 2];
    float bx = vb[e * 3], by = vb[e * 3 + 1], bz = vb[e * 3 + 2];
    float cx = vc[e * 3], cy = vc[e * 3 + 1], cz = vc[e * 3 + 2];
    float fx = cf0 * ax + cf1 * bx + cf2 * cx;
    float fy = cf0 * ay + cf1 * by + cf2 * cy;
    float fz = cf0 * az + cf1 * bz + cf2 * cz;
    float gx = ca0 * ax + ca1 * bx + ca2 * cx;
    float gy = ca0 * ay + ca1 * by + ca2 * cy;
    float gz = ca0 * az + ca1 * bz + ca2 * cz;
    float wsn = nw[s], wrn = nw[t];
    float sx = spos[e * 3], sy = spos[e * 3 + 1], sz = spos[e * 3 + 2];
    float rx = rpos[e * 3], ry = rpos[e * 3 + 1], rz = rpos[e * 3 + 2];
    float inv = 1.f / (wsn + wrn);
    float r0x = (wsn * sx + wrn * rx) * inv;
    float r0y = (wsn * sy + wrn * ry) * inv;
    float r0z = (wsn * sz + wrn * rz) * inv;
    float ddx = rx - r0x, ddy = ry - r0y, ddz = rz - r0z;
    float cxx = ddy * fz - ddz * fy;
    float cyy = ddz * fx - ddx * fz;
    float czz = ddx * fy - ddy * fx;
    float tx = gx - cxx * lam, ty = gy - cyy * lam, tz = gz - czz * lam;
    atomicAdd(&fsum[(size_t)t * 3 + 0], fx);
    atomicAdd(&fsum[(size_t)t * 3 + 1], fy);
    atomicAdd(&fsum[(size_t)t * 3 + 2], fz);
    atomicAdd(&tsum[(size_t)t * 3 + 0], tx);
    atomicAdd(&tsum[(size_t)t * 3 + 1], ty);
    atomicAdd(&tsum[(size_t)t * 3 + 2], tz);
  }
}

// ---------------- final node combine ----------------
__global__ __launch_bounds__(256) void k_final(const float* __restrict__ mi,
                                               const float* __restrict__ ii,
                                               const float* __restrict__ de,
                                               const float* __restrict__ fsum,
                                               const float* __restrict__ tsum,
                                               float* __restrict__ out) {
  int n = blockIdx.x * 256 + threadIdx.x;
  if (n >= N_NODES) return;
  float m = mi[n], iv = ii[n], d = de[n];
#pragma unroll
  for (int c = 0; c < 3; ++c) {
    out[(size_t)n * 3 + c] = m * fsum[(size_t)n * 3 + c] + d;
    out[(size_t)3 * N_NODES + (size_t)n * 3 + c] = iv * tsum[(size_t)n * 3 + c];
  }
}

// ---------------- launch ----------------
extern "C" void kernel_launch(void* const* d_in, const int* in_sizes, int n_in, void* d_out,
                              int out_size, void* d_ws, size_t ws_size, hipStream_t stream) {
  if (ws_size < WSEND) return;

  const int* ei = (const int*)d_in[0];
  const float* spos = (const float*)d_in[1];
  const float* rpos = (const float*)d_in[2];
  const float* dx = (const float*)d_in[3];
  const float* dt = (const float*)d_in[4];
  const float* va = (const float*)d_in[5];
  const float* vb = (const float*)d_in[6];
  const float* vc = (const float*)d_in[7];
  const float* svt = (const float*)d_in[8];
  const float* svtm1 = (const float*)d_in[9];
  const float* swt = (const float*)d_in[10];
  const float* rvt = (const float*)d_in[11];
  const float* rvtm1 = (const float*)d_in[12];
  const float* rwt = (const float*)d_in[13];
  const float* attr = (const float*)d_in[14];
  const float* NL = (const float*)d_in[15];
  const float* ef_W1 = (const float*)d_in[16];
  const float* ef_b1 = (const float*)d_in[17];
  const float* ef_W2 = (const float*)d_in[18];
  const float* ef_b2 = (const float*)d_in[19];
  const float* ef_g = (const float*)d_in[20];
  const float* ef_b = (const float*)d_in[21];
  const float* ee_W1 = (const float*)d_in[22];
  const float* ee_b1 = (const float*)d_in[23];
  const float* ee_W2 = (const float*)d_in[24];
  const float* ee_b2 = (const float*)d_in[25];
  const float* ee_g = (const float*)d_in[26];
  const float* ee_b = (const float*)d_in[27];
  const float* ie_W1 = (const float*)d_in[28];
  const float* ie_b1 = (const float*)d_in[29];
  const float* ie_W2 = (const float*)d_in[30];
  const float* ie_b2 = (const float*)d_in[31];
  const float* ie_g = (const float*)d_in[32];
  const float* ie_b = (const float*)d_in[33];
  const float* i1_W1 = (const float*)d_in[34];
  const float* i1_b1 = (const float*)d_in[35];
  const float* i1_W2 = (const float*)d_in[36];
  const float* i1_b2 = (const float*)d_in[37];
  const float* i2_W1 = (const float*)d_in[38];
  const float* i2_b1 = (const float*)d_in[39];
  const float* i2_W2 = (const float*)d_in[40];
  const float* i2_b2 = (const float*)d_in[41];
  const float* fs_W1 = (const float*)d_in[42];
  const float* fs_b1 = (const float*)d_in[43];
  const float* fs_W2 = (const float*)d_in[44];
  const float* fs_b2 = (const float*)d_in[45];
  const float* nw_W1 = (const float*)d_in[46];
  const float* nw_b1 = (const float*)d_in[47];
  const float* nw_W2 = (const float*)d_in[48];
  const float* nw_b2 = (const float*)d_in[49];
  const float* mi_W1 = (const float*)d_in[50];
  const float* mi_b1 = (const float*)d_in[51];
  const float* mi_W2 = (const float*)d_in[52];
  const float* mi_b2 = (const float*)d_in[53];
  const float* ii_W1 = (const float*)d_in[54];
  const float* ii_b1 = (const float*)d_in[55];
  const float* ii_W2 = (const float*)d_in[56];
  const float* ii_b2 = (const float*)d_in[57];
  const float* de_W1 = (const float*)d_in[58];
  const float* de_b1 = (const float*)d_in[59];
  const float* de_W2 = (const float*)d_in[60];
  const float* de_b2 = (const float*)d_in[61];

  float* out = (float*)d_out;
  char* ws = (char*)d_ws;
  unsigned short* W1P = (unsigned short*)(ws + OW1P);
  unsigned short* W2P = (unsigned short*)(ws + OW2P);
  unsigned short* W1D = (unsigned short*)(ws + OW1D);
  unsigned short* W2D = (unsigned short*)(ws + OW2D);
  unsigned short* W1E = (unsigned short*)(ws + OW1E);
  unsigned short* W2E = (unsigned short*)(ws + OW2E);
  unsigned short* W1C = (unsigned short*)(ws + OW1C);
  unsigned short* W2C = (unsigned short*)(ws + OW2C);
  uint32_t* slrp = (uint32_t*)(ws + OSLR);
  float* o_nw = (float*)(ws + ONW);
  float* o_mi = (float*)(ws + OMI);
  float* o_ii = (float*)(ws + OII);
  float* o_de = (float*)(ws + ODE);
  float* fsum = (float*)(ws + OFS);
  float* tsum = (float*)(ws + OTS);
  float* il = out + 6 * N_NODES;  // interaction_latent region (also e_lat temp)

  hipMemsetAsync(ws + OFS, 0, (size_t)N_NODES * 24, stream);  // fsum + tsum

  hipLaunchKernelGGL(k_prep, dim3(192), dim3(256), 0, stream, ie_W1, ie_W2,
                     i1_W1, i2_W1, fs_W1, i1_W2, i2_W2, fs_W2,
                     ef_W1, ef_W2, ee_W1, ee_W2,
                     W1P, W2P, W1D, W2D, W1E, W2E, W1C, W2C);

  hipLaunchKernelGGL(k_node, dim3(N_NODES / 32), dim3(256), 0, stream, NL,
                     nw_W1, nw_b1, nw_W2, nw_b2, mi_W1, mi_b1, mi_W2, mi_b2,
                     ii_W1, ii_b1, ii_W2, ii_b2, de_W1, de_b1, de_W2, de_b2,
                     o_nw, o_mi, o_ii, o_de);

  hipLaunchKernelGGL(k_ee_mfma, dim3(E_EDGES / 64), dim3(256), 0, stream, dx, dt, attr,
                     W1C, W2C, ee_b1, ee_b2, ee_g, ee_b, il);

  hipLaunchKernelGGL(k_ef_mfma, dim3(E_EDGES / 32), dim3(256), 0, stream, va, vb, vc,
                     svt, svtm1, swt, rvt, rvtm1, rwt,
                     W1E, W2E, ef_b1, ef_b2, ef_g, ef_b, slrp);

  hipLaunchKernelGGL(k_ie_mfma, dim3(E_EDGES / 64), dim3(256), 0, stream, ei, NL, slrp,
                     W1P, W2P, ie_b1, ie_b2, ie_g, ie_b, il);

  hipLaunchKernelGGL(k_dec_mfma, dim3(E_EDGES / 64), dim3(256), 0, stream, ei, il,
                     W1D, W2D, i1_b1, i2_b1, fs_b1, i1_b2, i2_b2, fs_b2,
                     o_nw, spos, rpos, va, vb, vc, fsum, tsum);

  hipLaunchKernelGGL(k_final, dim3((N_NODES + 255) / 256), dim3(256), 0, stream, o_mi, o_ii, o_de,
                     fsum, tsum, out);
}

// Round 5
// 1215.685 us; speedup vs baseline: 2.4234x; 1.1685x over previous
//
#include <hip/hip_runtime.h>
#include <hip/hip_fp16.h>
#include <stdint.h>

#define E_EDGES 400000
#define N_NODES 100000

// ---------------- workspace layout (bytes) ----------------
#define OW1P  ((size_t)0)                              // ushort[12*128*32] ie_W1 packed fp16 frag-order
#define OW2P  ((size_t)98304)                          // ushort[4*128*32]  ie_W2 packed fp16
#define OW1D  ((size_t)131072)                         // ushort[4*384*32]  dec W1cat packed fp16
#define OW2D  ((size_t)229376)                         // ushort[12*16*32]  dec W2cat packed fp16
#define OW1E  ((size_t)241664)                         // ushort[128*32]    ef_W1 packed (K 9->32 pad)
#define OW2E  ((size_t)249856)                         // ushort[4*128*32]  ef_W2 packed
#define OW1C  ((size_t)282624)                         // ushort[128*32]    ee_W1 packed (K 3->32 pad)
#define OW2C  ((size_t)290816)                         // ushort[4*128*32]  ee_W2 packed
#define OSLR  ((size_t)524288)                         // slr packed fp16, u32[E*64]
#define ONW   (OSLR + (size_t)E_EDGES * 64 * 4)        // float[N]  node_weights
#define OMI   (ONW + (size_t)N_NODES * 4)              // float[N]  m_inv
#define OII   (OMI + (size_t)N_NODES * 4)              // float[N]  i_inv
#define ODE   (OII + (size_t)N_NODES * 4)              // float[N]  de_out
#define OFS   (ODE + (size_t)N_NODES * 4)              // float[3N] fij sums
#define OTS   (OFS + (size_t)N_NODES * 12)             // float[3N] tau sums
#define WSEND (OTS + (size_t)N_NODES * 12)

typedef __attribute__((ext_vector_type(8))) _Float16 f16x8;
typedef __attribute__((ext_vector_type(4))) float f32x4;

// ---------------- helpers ----------------
__device__ __forceinline__ uint32_t f2h(float f) {
  return (uint32_t)__half_as_ushort(__float2half(f));   // RNE
}
__device__ __forceinline__ float wave_sum64(float v) {
#pragma unroll
  for (int off = 32; off > 0; off >>= 1) v += __shfl_xor(v, off, 64);
  return v;
}

// acc[8] pairs: a0 -> out col = lane, a1 -> out col = lane+64.
// W: fp32 row-major (Ka rows x 128 cols), read directly (L2-resident).
__device__ __forceinline__ void gemv8(const float* __restrict__ W,
                                      const float* __restrict__ xb, int xstride,
                                      int Ka, int lane, float* a0, float* a1) {
#pragma unroll 2
  for (int i = 0; i < Ka; i += 4) {
    float w0[4], w1[4];
#pragma unroll
    for (int u = 0; u < 4; ++u) {
      w0[u] = W[(size_t)(i + u) * 128 + lane];
      w1[u] = W[(size_t)(i + u) * 128 + 64 + lane];
    }
#pragma unroll
    for (int r = 0; r < 8; ++r) {
#pragma unroll
      for (int u = 0; u < 4; ++u) {
        float xv = xb[r * xstride + i + u];
        a0[r] = fmaf(xv, w0[u], a0[r]);
        a1[r] = fmaf(xv, w1[u], a1[r]);
      }
    }
  }
}

// copy 8 contiguous rows of 128 floats (4KB) global -> LDS, one wave
__device__ __forceinline__ void copy8x128(const float* __restrict__ src,
                                          float* __restrict__ dst, int lane) {
#pragma unroll
  for (int t = 0; t < 4; ++t) {
    float4 v = ((const float4*)src)[lane + 64 * t];
    ((float4*)dst)[lane + 64 * t] = v;
  }
}

// ---------------- node MLPs: nw, mi, ii, de (128->128->1), full fp32 (proven exact) ----------------
__global__ __launch_bounds__(256) void k_node(
    const float* __restrict__ NL,
    const float* __restrict__ nw_W1, const float* __restrict__ nw_b1,
    const float* __restrict__ nw_W2, const float* __restrict__ nw_b2,
    const float* __restrict__ mi_W1, const float* __restrict__ mi_b1,
    const float* __restrict__ mi_W2, const float* __restrict__ mi_b2,
    const float* __restrict__ ii_W1, const float* __restrict__ ii_b1,
    const float* __restrict__ ii_W2, const float* __restrict__ ii_b2,
    const float* __restrict__ de_W1, const float* __restrict__ de_b1,
    const float* __restrict__ de_W2, const float* __restrict__ de_b2,
    float* __restrict__ o_nw, float* __restrict__ o_mi, float* __restrict__ o_ii,
    float* __restrict__ o_de) {
  __shared__ float xb[4][8 * 128];
  int w = threadIdx.x >> 6, l = threadIdx.x & 63;
  int nb = blockIdx.x * 32 + w * 8;
  copy8x128(NL + (size_t)nb * 128, xb[w], l);
  __syncthreads();
  const float* W1s[4] = {nw_W1, mi_W1, ii_W1, de_W1};
  const float* B1[4] = {nw_b1, mi_b1, ii_b1, de_b1};
  const float* W2[4] = {nw_W2, mi_W2, ii_W2, de_W2};
  const float* B2[4] = {nw_b2, mi_b2, ii_b2, de_b2};
  float* OUT[4] = {o_nw, o_mi, o_ii, o_de};
#pragma unroll
  for (int m = 0; m < 4; ++m) {
    float b10 = B1[m][l], b11 = B1[m][l + 64];
    float a0[8], a1[8];
#pragma unroll
    for (int r = 0; r < 8; ++r) { a0[r] = b10; a1[r] = b11; }
    gemv8(W1s[m], xb[w], 128, 128, l, a0, a1);
    float w2a = W2[m][l], w2b = W2[m][l + 64];
    float b2 = B2[m][0];
    float y[8];
#pragma unroll
    for (int r = 0; r < 8; ++r) {
      float p = fmaxf(a0[r], 0.f) * w2a + fmaxf(a1[r], 0.f) * w2b;
      y[r] = wave_sum64(p) + b2;
    }
    if (l == 0) {
#pragma unroll
      for (int r = 0; r < 8; ++r) OUT[m][nb + r] = y[r];
    }
  }
}

// ---------------- prep: pack MLP weights into fp16 MFMA frag order ----------------
// frag layout: W[ks][c][kin] ushort; lane reads 8 fp16 at ((ks*COLS + c)*32 + lk*8).
__global__ __launch_bounds__(256) void k_prep(
    const float* __restrict__ W1, const float* __restrict__ W2,
    const float* __restrict__ i1W1, const float* __restrict__ i2W1,
    const float* __restrict__ fsW1,
    const float* __restrict__ i1W2, const float* __restrict__ i2W2,
    const float* __restrict__ fsW2,
    const float* __restrict__ efW1, const float* __restrict__ efW2,
    const float* __restrict__ eeW1, const float* __restrict__ eeW2,
    unsigned short* __restrict__ W1P, unsigned short* __restrict__ W2P,
    unsigned short* __restrict__ W1D, unsigned short* __restrict__ W2D,
    unsigned short* __restrict__ W1E, unsigned short* __restrict__ W2E,
    unsigned short* __restrict__ W1C, unsigned short* __restrict__ W2C) {
  int i = blockIdx.x * 256 + threadIdx.x;   // grid covers 49152
  if (i < 12 * 128 * 32) {                  // ie W1 (X col perm: [0,128) slr-interleaved)
    int kin = i & 31, c = (i >> 5) & 127, ks = i >> 12;
    int kx = ks * 32 + kin;
    int ko = (kx < 128) ? ((kx & 1) * 64 + (kx >> 1)) : kx;
    W1P[i] = (unsigned short)f2h(W1[(size_t)ko * 128 + c]);
  }
  if (i < 4 * 128 * 32) {                   // ie W2
    int kin = i & 31, c = (i >> 5) & 127, ks = i >> 12;
    W2P[i] = (unsigned short)f2h(W2[(size_t)(ks * 32 + kin) * 128 + c]);
  }
  if (i < 4 * 384 * 32) {                   // dec W1cat = [i1|i2|fs]
    int kin = i & 31;
    int rest = i >> 5;
    int c = rest % 384;
    int ks = rest / 384;
    int k = ks * 32 + kin;
    int head = c >> 7, ch = c & 127;
    const float* Wh = head == 0 ? i1W1 : head == 1 ? i2W1 : fsW1;
    W1D[i] = (unsigned short)f2h(Wh[(size_t)k * 128 + ch]);
  }
  if (i < 12 * 16 * 32) {                   // dec W2cat [384 x 16]
    int kin = i & 31;
    int rest = i >> 5;
    int col = rest & 15;
    int ks = rest >> 4;
    int k = ks * 32 + kin;
    float v = 0.f;
    if (k < 128) { if (col < 3) v = i1W2[(size_t)k * 3 + col]; }
    else if (k < 256) { if (col >= 3 && col < 6) v = i2W2[(size_t)(k - 128) * 3 + (col - 3)]; }
    else { if (col == 6) v = fsW2[k - 256]; }
    W2D[i] = (unsigned short)f2h(v);
  }
  if (i < 128 * 32) {                       // ef W1 (9 real K rows, pad to 32)
    int kin = i & 31, c = i >> 5;
    W1E[i] = (unsigned short)(kin < 9 ? f2h(efW1[(size_t)kin * 128 + c]) : 0);
  }
  if (i < 4 * 128 * 32) {                   // ef W2
    int kin = i & 31, c = (i >> 5) & 127, ks = i >> 12;
    W2E[i] = (unsigned short)f2h(efW2[(size_t)(ks * 32 + kin) * 128 + c]);
  }
  if (i < 128 * 32) {                       // ee W1 (3 real K rows, pad to 32)
    int kin = i & 31, c = i >> 5;
    W1C[i] = (unsigned short)(kin < 3 ? f2h(eeW1[(size_t)kin * 128 + c]) : 0);
  }
  if (i < 4 * 128 * 32) {                   // ee W2
    int kin = i & 31, c = (i >> 5) & 127, ks = i >> 12;
    W2C[i] = (unsigned short)f2h(eeW2[(size_t)(ks * 32 + kin) * 128 + c]);
  }
}

// ---------------- edge-feature encoder (ef): MFMA, 9 -> 128 -> 128, LN; slr = s+r ----------------
// 16 edges/block -> 32 rows: row<16 sender, row>=16 receiver (negated feats).
// LDS: Y fp32 [32][132] (16896) at 0; X-in [32][80] (2560) at 16896; H [32] pitch 256 swz (8192)
// at 19456. Total 27648 -> 5 blocks/CU.
#define EFY 0
#define EFX 16896
#define EFH 19456
__global__ __launch_bounds__(256) void k_ef_mfma(
    const float* __restrict__ va, const float* __restrict__ vb, const float* __restrict__ vc,
    const float* __restrict__ svt, const float* __restrict__ svtm1, const float* __restrict__ swt,
    const float* __restrict__ rvt, const float* __restrict__ rvtm1, const float* __restrict__ rwt,
    const unsigned short* __restrict__ W1E, const unsigned short* __restrict__ W2E,
    const float* __restrict__ b1, const float* __restrict__ b2,
    const float* __restrict__ g, const float* __restrict__ be, uint32_t* __restrict__ slrp) {
  __shared__ uint8_t lds[27648];
  int tid = threadIdx.x;
  int w = tid >> 6, l = tid & 63;
  int lrow = l & 15, lk = l >> 4;
  int base = blockIdx.x * 16;

  if (tid < 32) {
    int row = tid;
    int e = base + (row & 15);
    bool isR = row >= 16;
    const float* p0 = isR ? rvt : svt;
    const float* p1 = isR ? rvtm1 : svtm1;
    const float* p2 = isR ? rwt : swt;
    float sgn = isR ? -1.f : 1.f;
    float ax = va[e * 3], ay = va[e * 3 + 1], az = va[e * 3 + 2];
    float bx = vb[e * 3], by = vb[e * 3 + 1], bz = vb[e * 3 + 2];
    float cx = vc[e * 3], cy = vc[e * 3 + 1], cz = vc[e * 3 + 2];
    float f[10];
    const float* ps[3] = {p0, p1, p2};
#pragma unroll
    for (int q = 0; q < 3; ++q) {
      float vx = ps[q][e * 3], vy = ps[q][e * 3 + 1], vz = ps[q][e * 3 + 2];
      f[q * 3 + 0] = sgn * (vx * ax + vy * ay + vz * az);
      f[q * 3 + 1] = sgn * (vx * bx + vy * by + vz * bz);
      f[q * 3 + 2] = sgn * (vx * cx + vy * cy + vz * cz);
    }
    f[9] = 0.f;
    uint32_t* xr = (uint32_t*)(lds + EFX + (uint32_t)row * 80);
#pragma unroll
    for (int j = 0; j < 5; ++j) xr[j] = f2h(f[2 * j]) | (f2h(f[2 * j + 1]) << 16);
#pragma unroll
    for (int j = 5; j < 16; ++j) xr[j] = 0;
  }

  int wc = w * 32;
  f16x8 w2f[4][2];
#pragma unroll
  for (int ks = 0; ks < 4; ++ks)
#pragma unroll
    for (int ct = 0; ct < 2; ++ct)
      w2f[ks][ct] = *(const f16x8*)(W2E + ((size_t)(ks * 128 + wc + ct * 16 + lrow) * 32 + lk * 8));
  float b1c0 = b1[wc + lrow], b1c1 = b1[wc + 16 + lrow];
  float b2c0 = b2[wc + lrow], b2c1 = b2[wc + 16 + lrow];
  f16x8 bf0 = *(const f16x8*)(W1E + ((size_t)(wc + lrow) * 32 + lk * 8));
  f16x8 bf1 = *(const f16x8*)(W1E + ((size_t)(wc + 16 + lrow) * 32 + lk * 8));
  __syncthreads();

  // GEMM1: K=32
  f32x4 a1[2][2];
#pragma unroll
  for (int rt = 0; rt < 2; ++rt) {
    int row = rt * 16 + lrow;
    f16x8 af = *(const f16x8*)(lds + EFX + (uint32_t)row * 80 + lk * 16);
    a1[rt][0] = __builtin_amdgcn_mfma_f32_16x16x32_f16(af, bf0, (f32x4){0.f,0.f,0.f,0.f}, 0, 0, 0);
    a1[rt][1] = __builtin_amdgcn_mfma_f32_16x16x32_f16(af, bf1, (f32x4){0.f,0.f,0.f,0.f}, 0, 0, 0);
  }
#pragma unroll
  for (int rt = 0; rt < 2; ++rt)
#pragma unroll
    for (int ct = 0; ct < 2; ++ct) {
      float bc = ct ? b1c1 : b1c0;
      int col = wc + ct * 16 + lrow;
#pragma unroll
      for (int q = 0; q < 4; ++q) {
        int row = rt * 16 + lk * 4 + q;
        float h = fmaxf(a1[rt][ct][q] + bc, 0.f);
        uint32_t bo = ((uint32_t)row * 256 + (uint32_t)col * 2) ^ ((uint32_t)(row & 7) << 4);
        *(unsigned short*)(lds + EFH + bo) = (unsigned short)f2h(h);
      }
    }
  __syncthreads();

  // GEMM2: K=128
  f32x4 a2[2][2];
#pragma unroll
  for (int rt = 0; rt < 2; ++rt)
#pragma unroll
    for (int ct = 0; ct < 2; ++ct) a2[rt][ct] = (f32x4){0.f, 0.f, 0.f, 0.f};
#pragma unroll
  for (int ks = 0; ks < 4; ++ks) {
#pragma unroll
    for (int rt = 0; rt < 2; ++rt) {
      int row = rt * 16 + lrow;
      uint32_t bo = ((uint32_t)row * 256 + (uint32_t)(ks * 64 + lk * 16)) ^ ((uint32_t)(row & 7) << 4);
      f16x8 af = *(const f16x8*)(lds + EFH + bo);
      a2[rt][0] = __builtin_amdgcn_mfma_f32_16x16x32_f16(af, w2f[ks][0], a2[rt][0], 0, 0, 0);
      a2[rt][1] = __builtin_amdgcn_mfma_f32_16x16x32_f16(af, w2f[ks][1], a2[rt][1], 0, 0, 0);
    }
  }
  float* Ys = (float*)(lds + EFY);
#pragma unroll
  for (int rt = 0; rt < 2; ++rt)
#pragma unroll
    for (int ct = 0; ct < 2; ++ct) {
      float bc = ct ? b2c1 : b2c0;
      int col = wc + ct * 16 + lrow;
#pragma unroll
      for (int q = 0; q < 4; ++q) {
        int row = rt * 16 + lk * 4 + q;
        Ys[row * 132 + col] = a2[rt][ct][q] + bc;
      }
    }
  __syncthreads();

  // LN in-place (8 rows/wave)
  float gl0 = g[l], gl1 = g[l + 64], bl0 = be[l], bl1 = be[l + 64];
#pragma unroll
  for (int r8 = 0; r8 < 8; ++r8) {
    int row = w * 8 + r8;
    float y0 = Ys[row * 132 + l], y1 = Ys[row * 132 + 64 + l];
    float s = wave_sum64(y0 + y1);
    float s2 = wave_sum64(y0 * y0 + y1 * y1);
    float mu = s * 0.0078125f;
    float var = s2 * 0.0078125f - mu * mu;
    float rstd = rsqrtf(var + 1e-5f);
    Ys[row * 132 + l] = (y0 - mu) * rstd * gl0 + bl0;
    Ys[row * 132 + 64 + l] = (y1 - mu) * rstd * gl1 + bl1;
  }
  __syncthreads();
  if (w < 2) {
#pragma unroll
    for (int r8 = 0; r8 < 8; ++r8) {
      int row = w * 8 + r8;
      float s0 = Ys[row * 132 + l] + Ys[(row + 16) * 132 + l];
      float s1 = Ys[row * 132 + 64 + l] + Ys[(row + 16) * 132 + 64 + l];
      slrp[(size_t)(base + row) * 64 + l] = f2h(s0) | (f2h(s1) << 16);
    }
  }
}

// ---------------- fused edge encoder + interaction encoder ----------------
// 32 edges/block. Phase 1: ee MLP (3->128->128, LN) -> e_lat in regs. Phase 2: stage X
// (slr | NL[s]+NL[t] | e_lat), ie MLP (384->128->128, LN) -> il.
// LDS: XI=0: X-ie fp16 [32] pitch 768 swz (24576; doubles as Y fp32 [32][132] in LN phases);
// HH=24576: H fp16 [32] pitch 256 swz (8192); XE=32768: X-ee [32][80] (2560);
// EIX=35328: int[64]. Total 35584 -> 4 blocks/CU.
#define XI 0
#define HH 24576
#define XE 32768
#define EIX 35328
__global__ __launch_bounds__(256) void k_ie_fused(
    const int* __restrict__ ei, const float* __restrict__ NL,
    const uint32_t* __restrict__ slrp,
    const float* __restrict__ dxp, const float* __restrict__ dtp, const float* __restrict__ attr,
    const unsigned short* __restrict__ W1C, const unsigned short* __restrict__ W2C,
    const float* __restrict__ eb1, const float* __restrict__ eb2,
    const float* __restrict__ eg, const float* __restrict__ ebe,
    const unsigned short* __restrict__ W1P, const unsigned short* __restrict__ W2P,
    const float* __restrict__ b1, const float* __restrict__ b2,
    const float* __restrict__ g, const float* __restrict__ be,
    float* __restrict__ il) {
  __shared__ uint8_t lds[35584];
  int tid = threadIdx.x;
  int w = tid >> 6, l = tid & 63;
  int lrow = l & 15, lk = l >> 4;
  int base = blockIdx.x * 32;
  int wc = w * 32;

  int* eis = (int*)(lds + EIX);
  int* eit = eis + 32;
  if (tid < 32) {
    eis[tid] = ei[base + tid];
    eit[tid] = ei[E_EDGES + base + tid];
    // stage ee input features
    int e = base + tid;
    float a0 = dxp[e * 3], a1v = dxp[e * 3 + 1], a2 = dxp[e * 3 + 2];
    float t0 = dtp[e * 3], t1 = dtp[e * 3 + 1], t2 = dtp[e * 3 + 2];
    float f0 = sqrtf(a0 * a0 + a1v * a1v + a2 * a2);
    float f1 = sqrtf(t0 * t0 + t1 * t1 + t2 * t2);
    float f2v = attr[e];
    uint32_t* xr = (uint32_t*)(lds + XE + (uint32_t)tid * 80);
    xr[0] = f2h(f0) | (f2h(f1) << 16);
    xr[1] = f2h(f2v);
#pragma unroll
    for (int j = 2; j < 16; ++j) xr[j] = 0;
  }

  // ---- ee phase ----
  f16x8 w2fe[4][2];
#pragma unroll
  for (int ks = 0; ks < 4; ++ks)
#pragma unroll
    for (int ct = 0; ct < 2; ++ct)
      w2fe[ks][ct] = *(const f16x8*)(W2C + ((size_t)(ks * 128 + wc + ct * 16 + lrow) * 32 + lk * 8));
  float eb1c0 = eb1[wc + lrow], eb1c1 = eb1[wc + 16 + lrow];
  float eb2c0 = eb2[wc + lrow], eb2c1 = eb2[wc + 16 + lrow];
  f16x8 bfe0 = *(const f16x8*)(W1C + ((size_t)(wc + lrow) * 32 + lk * 8));
  f16x8 bfe1 = *(const f16x8*)(W1C + ((size_t)(wc + 16 + lrow) * 32 + lk * 8));
  __syncthreads();

  f32x4 aE[2][2];
#pragma unroll
  for (int rt = 0; rt < 2; ++rt) {
    int row = rt * 16 + lrow;
    f16x8 af = *(const f16x8*)(lds + XE + (uint32_t)row * 80 + lk * 16);
    aE[rt][0] = __builtin_amdgcn_mfma_f32_16x16x32_f16(af, bfe0, (f32x4){0.f,0.f,0.f,0.f}, 0, 0, 0);
    aE[rt][1] = __builtin_amdgcn_mfma_f32_16x16x32_f16(af, bfe1, (f32x4){0.f,0.f,0.f,0.f}, 0, 0, 0);
  }
#pragma unroll
  for (int rt = 0; rt < 2; ++rt)
#pragma unroll
    for (int ct = 0; ct < 2; ++ct) {
      float bc = ct ? eb1c1 : eb1c0;
      int col = wc + ct * 16 + lrow;
#pragma unroll
      for (int q = 0; q < 4; ++q) {
        int row = rt * 16 + lk * 4 + q;
        float h = fmaxf(aE[rt][ct][q] + bc, 0.f);
        uint32_t bo = ((uint32_t)row * 256 + (uint32_t)col * 2) ^ ((uint32_t)(row & 7) << 4);
        *(unsigned short*)(lds + HH + bo) = (unsigned short)f2h(h);
      }
    }
  __syncthreads();

  f32x4 aE2[2][2];
#pragma unroll
  for (int rt = 0; rt < 2; ++rt)
#pragma unroll
    for (int ct = 0; ct < 2; ++ct) aE2[rt][ct] = (f32x4){0.f, 0.f, 0.f, 0.f};
#pragma unroll
  for (int ks = 0; ks < 4; ++ks) {
#pragma unroll
    for (int rt = 0; rt < 2; ++rt) {
      int row = rt * 16 + lrow;
      uint32_t bo = ((uint32_t)row * 256 + (uint32_t)(ks * 64 + lk * 16)) ^ ((uint32_t)(row & 7) << 4);
      f16x8 af = *(const f16x8*)(lds + HH + bo);
      aE2[rt][0] = __builtin_amdgcn_mfma_f32_16x16x32_f16(af, w2fe[ks][0], aE2[rt][0], 0, 0, 0);
      aE2[rt][1] = __builtin_amdgcn_mfma_f32_16x16x32_f16(af, w2fe[ks][1], aE2[rt][1], 0, 0, 0);
    }
  }
  float* Ys = (float*)(lds + XI);
#pragma unroll
  for (int rt = 0; rt < 2; ++rt)
#pragma unroll
    for (int ct = 0; ct < 2; ++ct) {
      float bc = ct ? eb2c1 : eb2c0;
      int col = wc + ct * 16 + lrow;
#pragma unroll
      for (int q = 0; q < 4; ++q) {
        int row = rt * 16 + lk * 4 + q;
        Ys[row * 132 + col] = aE2[rt][ct][q] + bc;
      }
    }
  __syncthreads();

  // LN-ee -> e_lat in regs (8 rows/wave)
  float el0[8], el1[8];
  {
    float gl0 = eg[l], gl1 = eg[l + 64], bl0 = ebe[l], bl1 = ebe[l + 64];
#pragma unroll
    for (int r8 = 0; r8 < 8; ++r8) {
      int row = w * 8 + r8;
      float y0 = Ys[row * 132 + l], y1 = Ys[row * 132 + 64 + l];
      float s = wave_sum64(y0 + y1);
      float s2 = wave_sum64(y0 * y0 + y1 * y1);
      float mu = s * 0.0078125f;
      float var = s2 * 0.0078125f - mu * mu;
      float rstd = rsqrtf(var + 1e-5f);
      el0[r8] = (y0 - mu) * rstd * gl0 + bl0;
      el1[r8] = (y1 - mu) * rstd * gl1 + bl1;
    }
  }
  __syncthreads();   // all Y reads done before X staging overwrites XI

  // ---- stage X-ie ----
  // seg A: slr (interleaved col order, matched by W1P perm)
#pragma unroll
  for (int i = tid; i < 32 * 64; i += 256) {
    int r = i >> 6, c = i & 63;
    uint32_t bo = ((uint32_t)r * 768 + (uint32_t)c * 4) ^ ((uint32_t)(r & 7) << 4);
    *(uint32_t*)(lds + XI + bo) = slrp[(size_t)(base + r) * 64 + c];
  }
  // seg B: NL[s]+NL[t]
  const float2* NL2 = (const float2*)NL;
#pragma unroll
  for (int i = tid; i < 32 * 64; i += 256) {
    int r = i >> 6, c = i & 63;
    float2 a = NL2[(size_t)eis[r] * 64 + c];
    float2 bq = NL2[(size_t)eit[r] * 64 + c];
    uint32_t p = f2h(a.x + bq.x) | (f2h(a.y + bq.y) << 16);
    uint32_t bo = ((uint32_t)r * 768 + 256u + (uint32_t)c * 4) ^ ((uint32_t)(r & 7) << 4);
    *(uint32_t*)(lds + XI + bo) = p;
  }
  // seg C: e_lat from regs (each wave owns its 8 rows)
#pragma unroll
  for (int r8 = 0; r8 < 8; ++r8) {
    int row = w * 8 + r8;
    uint32_t bo0 = ((uint32_t)row * 768 + 512u + (uint32_t)l * 2) ^ ((uint32_t)(row & 7) << 4);
    uint32_t bo1 = ((uint32_t)row * 768 + 512u + (uint32_t)(l + 64) * 2) ^ ((uint32_t)(row & 7) << 4);
    *(unsigned short*)(lds + XI + bo0) = (unsigned short)f2h(el0[r8]);
    *(unsigned short*)(lds + XI + bo1) = (unsigned short)f2h(el1[r8]);
  }

  f16x8 w2f[4][2];
#pragma unroll
  for (int ks = 0; ks < 4; ++ks)
#pragma unroll
    for (int ct = 0; ct < 2; ++ct)
      w2f[ks][ct] = *(const f16x8*)(W2P + ((size_t)(ks * 128 + wc + ct * 16 + lrow) * 32 + lk * 8));
  float b1c0 = b1[wc + lrow], b1c1 = b1[wc + 16 + lrow];
  float b2c0 = b2[wc + lrow], b2c1 = b2[wc + 16 + lrow];
  __syncthreads();

  // ---- ie GEMM1: K=384 ----
  f32x4 acc[2][2];
#pragma unroll
  for (int rt = 0; rt < 2; ++rt)
#pragma unroll
    for (int ct = 0; ct < 2; ++ct) acc[rt][ct] = (f32x4){0.f, 0.f, 0.f, 0.f};
#pragma unroll 2
  for (int ks = 0; ks < 12; ++ks) {
    f16x8 bf0 = *(const f16x8*)(W1P + ((size_t)(ks * 128 + wc + lrow) * 32 + lk * 8));
    f16x8 bf1 = *(const f16x8*)(W1P + ((size_t)(ks * 128 + wc + 16 + lrow) * 32 + lk * 8));
#pragma unroll
    for (int rt = 0; rt < 2; ++rt) {
      int row = rt * 16 + lrow;
      uint32_t bo = ((uint32_t)row * 768 + (uint32_t)(ks * 64 + lk * 16)) ^ ((uint32_t)(row & 7) << 4);
      f16x8 af = *(const f16x8*)(lds + XI + bo);
      acc[rt][0] = __builtin_amdgcn_mfma_f32_16x16x32_f16(af, bf0, acc[rt][0], 0, 0, 0);
      acc[rt][1] = __builtin_amdgcn_mfma_f32_16x16x32_f16(af, bf1, acc[rt][1], 0, 0, 0);
    }
  }
#pragma unroll
  for (int rt = 0; rt < 2; ++rt)
#pragma unroll
    for (int ct = 0; ct < 2; ++ct) {
      float bc = ct ? b1c1 : b1c0;
      int col = wc + ct * 16 + lrow;
#pragma unroll
      for (int q = 0; q < 4; ++q) {
        int row = rt * 16 + lk * 4 + q;
        float h = fmaxf(acc[rt][ct][q] + bc, 0.f);
        uint32_t bo = ((uint32_t)row * 256 + (uint32_t)col * 2) ^ ((uint32_t)(row & 7) << 4);
        *(unsigned short*)(lds + HH + bo) = (unsigned short)f2h(h);
      }
    }
  __syncthreads();

  // ---- ie GEMM2: K=128 ----
  f32x4 acc2[2][2];
#pragma unroll
  for (int rt = 0; rt < 2; ++rt)
#pragma unroll
    for (int ct = 0; ct < 2; ++ct) acc2[rt][ct] = (f32x4){0.f, 0.f, 0.f, 0.f};
#pragma unroll
  for (int ks = 0; ks < 4; ++ks) {
#pragma unroll
    for (int rt = 0; rt < 2; ++rt) {
      int row = rt * 16 + lrow;
      uint32_t bo = ((uint32_t)row * 256 + (uint32_t)(ks * 64 + lk * 16)) ^ ((uint32_t)(row & 7) << 4);
      f16x8 af = *(const f16x8*)(lds + HH + bo);
      acc2[rt][0] = __builtin_amdgcn_mfma_f32_16x16x32_f16(af, w2f[ks][0], acc2[rt][0], 0, 0, 0);
      acc2[rt][1] = __builtin_amdgcn_mfma_f32_16x16x32_f16(af, w2f[ks][1], acc2[rt][1], 0, 0, 0);
    }
  }
  // Y-ie -> fp32 LDS (XI region; all X reads completed at the H barrier)
#pragma unroll
  for (int rt = 0; rt < 2; ++rt)
#pragma unroll
    for (int ct = 0; ct < 2; ++ct) {
      float bc = ct ? b2c1 : b2c0;
      int col = wc + ct * 16 + lrow;
#pragma unroll
      for (int q = 0; q < 4; ++q) {
        int row = rt * 16 + lk * 4 + q;
        Ys[row * 132 + col] = acc2[rt][ct][q] + bc;
      }
    }
  __syncthreads();

  // LN-ie + store (8 rows/wave)
  float gl0 = g[l], gl1 = g[l + 64], bl0 = be[l], bl1 = be[l + 64];
#pragma unroll
  for (int r8 = 0; r8 < 8; ++r8) {
    int row = w * 8 + r8;
    float y0 = Ys[row * 132 + l], y1 = Ys[row * 132 + 64 + l];
    float s = wave_sum64(y0 + y1);
    float s2 = wave_sum64(y0 * y0 + y1 * y1);
    float mu = s * 0.0078125f;
    float var = s2 * 0.0078125f - mu * mu;
    float rstd = rsqrtf(var + 1e-5f);
    size_t o = (size_t)(base + row) * 128;
    il[o + l] = (y0 - mu) * rstd * gl0 + bl0;
    il[o + 64 + l] = (y1 - mu) * rstd * gl1 + bl1;
  }
}

// ---------------- decoder heads via MFMA + physics + scatter (32 edges/block) ----------------
// LDS: H fp16 [32] pitch 768 swz (24576) at 0; X fp16 [32] pitch 256 swz (8192) at 24576.
// Y fp32 [32][17] reuses X region after H barrier. 32768 B -> 5 blocks/CU.
__global__ __launch_bounds__(256) void k_dec_mfma(
    const int* __restrict__ ei, const float* __restrict__ il,
    const unsigned short* __restrict__ W1D, const unsigned short* __restrict__ W2D,
    const float* __restrict__ i1b1, const float* __restrict__ i2b1,
    const float* __restrict__ fsb1,
    const float* __restrict__ i1b2, const float* __restrict__ i2b2,
    const float* __restrict__ fsb2,
    const float* __restrict__ nw, const float* __restrict__ spos, const float* __restrict__ rpos,
    const float* __restrict__ va, const float* __restrict__ vb, const float* __restrict__ vc,
    float* __restrict__ fsum, float* __restrict__ tsum) {
  __shared__ uint8_t lds[32768];
  int tid = threadIdx.x;
  int w = tid >> 6, l = tid & 63;
  int lrow = l & 15, lk = l >> 4;
  int base = blockIdx.x * 32;

  const float2* IL2 = (const float2*)il;
#pragma unroll
  for (int i = tid; i < 32 * 64; i += 256) {
    int r = i >> 6, c = i & 63;
    float2 a = IL2[(size_t)(base + r) * 64 + c];
    uint32_t p = f2h(a.x) | (f2h(a.y) << 16);
    uint32_t bo = ((uint32_t)r * 256 + (uint32_t)c * 4) ^ ((uint32_t)(r & 7) << 4);
    *(uint32_t*)(lds + 24576 + bo) = p;
  }

  float b1c[6];
#pragma unroll
  for (int ct = 0; ct < 6; ++ct) {
    int c = w * 96 + ct * 16 + lrow;
    const float* bsel = (c < 128) ? i1b1 : (c < 256) ? i2b1 : fsb1;
    b1c[ct] = bsel[c & 127];
  }
  f16x8 w2f[12];
#pragma unroll
  for (int ks = 0; ks < 12; ++ks)
    w2f[ks] = *(const f16x8*)(W2D + ((size_t)(ks * 16 + lrow) * 32 + lk * 8));
  float b2c = lrow < 3 ? i1b2[lrow] : lrow < 6 ? i2b2[lrow - 3] : lrow == 6 ? fsb2[0] : 0.f;
  __syncthreads();

  // GEMM1: 32 rows x 96 cols (per wave), K=128
  f32x4 acc[2][6];
#pragma unroll
  for (int rt = 0; rt < 2; ++rt)
#pragma unroll
    for (int ct = 0; ct < 6; ++ct) acc[rt][ct] = (f32x4){0.f, 0.f, 0.f, 0.f};
#pragma unroll
  for (int ks = 0; ks < 4; ++ks) {
    f16x8 bf[6];
#pragma unroll
    for (int ct = 0; ct < 6; ++ct)
      bf[ct] = *(const f16x8*)(W1D + ((size_t)(ks * 384 + w * 96 + ct * 16 + lrow) * 32 + lk * 8));
#pragma unroll
    for (int rt = 0; rt < 2; ++rt) {
      int row = rt * 16 + lrow;
      uint32_t bo = ((uint32_t)row * 256 + (uint32_t)(ks * 64 + lk * 16)) ^ ((uint32_t)(row & 7) << 4);
      f16x8 af = *(const f16x8*)(lds + 24576 + bo);
#pragma unroll
      for (int ct = 0; ct < 6; ++ct)
        acc[rt][ct] = __builtin_amdgcn_mfma_f32_16x16x32_f16(af, bf[ct], acc[rt][ct], 0, 0, 0);
    }
  }
#pragma unroll
  for (int rt = 0; rt < 2; ++rt)
#pragma unroll
    for (int ct = 0; ct < 6; ++ct) {
      int col = w * 96 + ct * 16 + lrow;
#pragma unroll
      for (int q = 0; q < 4; ++q) {
        int row = rt * 16 + lk * 4 + q;
        float h = fmaxf(acc[rt][ct][q] + b1c[ct], 0.f);
        uint32_t bo = ((uint32_t)row * 768 + (uint32_t)col * 2) ^ ((uint32_t)(row & 7) << 4);
        *(unsigned short*)(lds + bo) = (unsigned short)f2h(h);
      }
    }
  __syncthreads();

  // GEMM2: Y[32][16] = H @ W2cat, K=384; waves 0,1 own 16 rows each
  float* Ys = (float*)(lds + 24576);  // [32][17]
  if (w < 2) {
    f32x4 acc2 = (f32x4){0.f, 0.f, 0.f, 0.f};
#pragma unroll
    for (int ks = 0; ks < 12; ++ks) {
      int row = w * 16 + lrow;
      uint32_t bo = ((uint32_t)row * 768 + (uint32_t)(ks * 64 + lk * 16)) ^ ((uint32_t)(row & 7) << 4);
      f16x8 af = *(const f16x8*)(lds + bo);
      acc2 = __builtin_amdgcn_mfma_f32_16x16x32_f16(af, w2f[ks], acc2, 0, 0, 0);
    }
#pragma unroll
    for (int q = 0; q < 4; ++q) {
      int row = w * 16 + lk * 4 + q;
      Ys[row * 17 + lrow] = acc2[q] + b2c;
    }
  }
  __syncthreads();

  if (tid < 32) {
    int e = base + tid;
    int s = ei[e], t = ei[E_EDGES + e];
    float cf0 = Ys[tid * 17 + 0], cf1 = Ys[tid * 17 + 1], cf2 = Ys[tid * 17 + 2];
    float ca0 = Ys[tid * 17 + 3], ca1 = Ys[tid * 17 + 4], ca2 = Ys[tid * 17 + 5];
    float lam = Ys[tid * 17 + 6];
    float ax = va[e * 3], ay = va[e * 3 + 1], az = va[e * 3 + 2];
    float bx = vb[e * 3], by = vb[e * 3 + 1], bz = vb[e * 3 + 2];
    float cx = vc[e * 3], cy = vc[e * 3 + 1], cz = vc[e * 3 + 2];
    float fx = cf0 * ax + cf1 * bx + cf2 * cx;
    float fy = cf0 * ay + cf1 * by + cf2 * cy;
    float fz = cf0 * az + cf1 * bz + cf2 * cz;
    float gx = ca0 * ax + ca1 * bx + ca2 * cx;
    float gy = ca0 * ay + ca1 * by + ca2 * cy;
    float gz = ca0 * az + ca1 * bz + ca2 * cz;
    float wsn = nw[s], wrn = nw[t];
    float sx = spos[e * 3], sy = spos[e * 3 + 1], sz = spos[e * 3 + 2];
    float rx = rpos[e * 3], ry = rpos[e * 3 + 1], rz = rpos[e * 3 + 2];
    float inv = 1.f / (wsn + wrn);
    float r0x = (wsn * sx + wrn * rx) * inv;
    float r0y = (wsn * sy + wrn * ry) * inv;
    float r0z = (wsn * sz + wrn * rz) * inv;
    float ddx = rx - r0x, ddy = ry - r0y, ddz = rz - r0z;
    float cxx = ddy * fz - ddz * fy;
    float cyy = ddz * fx - ddx * fz;
    float czz = ddx * fy - ddy * fx;
    float tx = gx - cxx * lam, ty = gy - cyy * lam, tz = gz - czz * lam;
    atomicAdd(&fsum[(size_t)t * 3 + 0], fx);
    atomicAdd(&fsum[(size_t)t * 3 + 1], fy);
    atomicAdd(&fsum[(size_t)t * 3 + 2], fz);
    atomicAdd(&tsum[(size_t)t * 3 + 0], tx);
    atomicAdd(&tsum[(size_t)t * 3 + 1], ty);
    atomicAdd(&tsum[(size_t)t * 3 + 2], tz);
  }
}

// ---------------- final node combine ----------------
__global__ __launch_bounds__(256) void k_final(const float* __restrict__ mi,
                                               const float* __restrict__ ii,
                                               const float* __restrict__ de,
                                               const float* __restrict__ fsum,
                                               const float* __restrict__ tsum,
                                               float* __restrict__ out) {
  int n = blockIdx.x * 256 + threadIdx.x;
  if (n >= N_NODES) return;
  float m = mi[n], iv = ii[n], d = de[n];
#pragma unroll
  for (int c = 0; c < 3; ++c) {
    out[(size_t)n * 3 + c] = m * fsum[(size_t)n * 3 + c] + d;
    out[(size_t)3 * N_NODES + (size_t)n * 3 + c] = iv * tsum[(size_t)n * 3 + c];
  }
}

// ---------------- launch ----------------
extern "C" void kernel_launch(void* const* d_in, const int* in_sizes, int n_in, void* d_out,
                              int out_size, void* d_ws, size_t ws_size, hipStream_t stream) {
  if (ws_size < WSEND) return;

  const int* ei = (const int*)d_in[0];
  const float* spos = (const float*)d_in[1];
  const float* rpos = (const float*)d_in[2];
  const float* dx = (const float*)d_in[3];
  const float* dt = (const float*)d_in[4];
  const float* va = (const float*)d_in[5];
  const float* vb = (const float*)d_in[6];
  const float* vc = (const float*)d_in[7];
  const float* svt = (const float*)d_in[8];
  const float* svtm1 = (const float*)d_in[9];
  const float* swt = (const float*)d_in[10];
  const float* rvt = (const float*)d_in[11];
  const float* rvtm1 = (const float*)d_in[12];
  const float* rwt = (const float*)d_in[13];
  const float* attr = (const float*)d_in[14];
  const float* NL = (const float*)d_in[15];
  const float* ef_W1 = (const float*)d_in[16];
  const float* ef_b1 = (const float*)d_in[17];
  const float* ef_W2 = (const float*)d_in[18];
  const float* ef_b2 = (const float*)d_in[19];
  const float* ef_g = (const float*)d_in[20];
  const float* ef_b = (const float*)d_in[21];
  const float* ee_W1 = (const float*)d_in[22];
  const float* ee_b1 = (const float*)d_in[23];
  const float* ee_W2 = (const float*)d_in[24];
  const float* ee_b2 = (const float*)d_in[25];
  const float* ee_g = (const float*)d_in[26];
  const float* ee_b = (const float*)d_in[27];
  const float* ie_W1 = (const float*)d_in[28];
  const float* ie_b1 = (const float*)d_in[29];
  const float* ie_W2 = (const float*)d_in[30];
  const float* ie_b2 = (const float*)d_in[31];
  const float* ie_g = (const float*)d_in[32];
  const float* ie_b = (const float*)d_in[33];
  const float* i1_W1 = (const float*)d_in[34];
  const float* i1_b1 = (const float*)d_in[35];
  const float* i1_W2 = (const float*)d_in[36];
  const float* i1_b2 = (const float*)d_in[37];
  const float* i2_W1 = (const float*)d_in[38];
  const float* i2_b1 = (const float*)d_in[39];
  const float* i2_W2 = (const float*)d_in[40];
  const float* i2_b2 = (const float*)d_in[41];
  const float* fs_W1 = (const float*)d_in[42];
  const float* fs_b1 = (const float*)d_in[43];
  const float* fs_W2 = (const float*)d_in[44];
  const float* fs_b2 = (const float*)d_in[45];
  const float* nw_W1 = (const float*)d_in[46];
  const float* nw_b1 = (const float*)d_in[47];
  const float* nw_W2 = (const float*)d_in[48];
  const float* nw_b2 = (const float*)d_in[49];
  const float* mi_W1 = (const float*)d_in[50];
  const float* mi_b1 = (const float*)d_in[51];
  const float* mi_W2 = (const float*)d_in[52];
  const float* mi_b2 = (const float*)d_in[53];
  const float* ii_W1 = (const float*)d_in[54];
  const float* ii_b1 = (const float*)d_in[55];
  const float* ii_W2 = (const float*)d_in[56];
  const float* ii_b2 = (const float*)d_in[57];
  const float* de_W1 = (const float*)d_in[58];
  const float* de_b1 = (const float*)d_in[59];
  const float* de_W2 = (const float*)d_in[60];
  const float* de_b2 = (const float*)d_in[61];

  float* out = (float*)d_out;
  char* ws = (char*)d_ws;
  unsigned short* W1P = (unsigned short*)(ws + OW1P);
  unsigned short* W2P = (unsigned short*)(ws + OW2P);
  unsigned short* W1D = (unsigned short*)(ws + OW1D);
  unsigned short* W2D = (unsigned short*)(ws + OW2D);
  unsigned short* W1E = (unsigned short*)(ws + OW1E);
  unsigned short* W2E = (unsigned short*)(ws + OW2E);
  unsigned short* W1C = (unsigned short*)(ws + OW1C);
  unsigned short* W2C = (unsigned short*)(ws + OW2C);
  uint32_t* slrp = (uint32_t*)(ws + OSLR);
  float* o_nw = (float*)(ws + ONW);
  float* o_mi = (float*)(ws + OMI);
  float* o_ii = (float*)(ws + OII);
  float* o_de = (float*)(ws + ODE);
  float* fsum = (float*)(ws + OFS);
  float* tsum = (float*)(ws + OTS);
  float* il = out + 6 * N_NODES;  // interaction_latent output region

  hipMemsetAsync(ws + OFS, 0, (size_t)N_NODES * 24, stream);  // fsum + tsum

  hipLaunchKernelGGL(k_prep, dim3(192), dim3(256), 0, stream, ie_W1, ie_W2,
                     i1_W1, i2_W1, fs_W1, i1_W2, i2_W2, fs_W2,
                     ef_W1, ef_W2, ee_W1, ee_W2,
                     W1P, W2P, W1D, W2D, W1E, W2E, W1C, W2C);

  hipLaunchKernelGGL(k_node, dim3(N_NODES / 32), dim3(256), 0, stream, NL,
                     nw_W1, nw_b1, nw_W2, nw_b2, mi_W1, mi_b1, mi_W2, mi_b2,
                     ii_W1, ii_b1, ii_W2, ii_b2, de_W1, de_b1, de_W2, de_b2,
                     o_nw, o_mi, o_ii, o_de);

  hipLaunchKernelGGL(k_ef_mfma, dim3(E_EDGES / 16), dim3(256), 0, stream, va, vb, vc,
                     svt, svtm1, swt, rvt, rvtm1, rwt,
                     W1E, W2E, ef_b1, ef_b2, ef_g, ef_b, slrp);

  hipLaunchKernelGGL(k_ie_fused, dim3(E_EDGES / 32), dim3(256), 0, stream, ei, NL, slrp,
                     dx, dt, attr, W1C, W2C, ee_b1, ee_b2, ee_g, ee_b,
                     W1P, W2P, ie_b1, ie_b2, ie_g, ie_b, il);

  hipLaunchKernelGGL(k_dec_mfma, dim3(E_EDGES / 32), dim3(256), 0, stream, ei, il,
                     W1D, W2D, i1_b1, i2_b1, fs_b1, i1_b2, i2_b2, fs_b2,
                     o_nw, spos, rpos, va, vb, vc, fsum, tsum);

  hipLaunchKernelGGL(k_final, dim3((N_NODES + 255) / 256), dim3(256), 0, stream, o_mi, o_ii, o_de,
                     fsum, tsum, out);
}